// Round 1
// baseline (6862.988 us; speedup 1.0000x reference)
//
#include <hip/hip_runtime.h>
#include <hip/hip_bf16.h>

// Problem constants (from reference)
#define NN 100000
#define EE 1600000
#define BB 256
#define F_NODE 35
#define F_EDGE 10
#define HH 64
#define IN_DIM 138          // 2*H + F_EDGE
#define ZROW 140            // padded z row in LDS
#define N_CONV 3
#define EPSBN 1e-5f

__device__ __forceinline__ float softplus_f(float x) {
    // log1p(exp(x)), stable: exp underflows to 0 for very negative x
    if (x > 20.0f) return x;
    return log1pf(__expf(x));
}

__device__ __forceinline__ float sigmoid_f(float x) {
    return 1.0f / (1.0f + __expf(-x));
}

// h[N,64] = nf[N,35] @ W[35,64] + b
__global__ __launch_bounds__(256)
void embed_kernel(const float* __restrict__ nf, const float* __restrict__ w,
                  const float* __restrict__ bias, float* __restrict__ h, int n) {
    __shared__ float wl[F_NODE * HH];
    int tid = threadIdx.x;
    for (int i = tid; i < F_NODE * HH; i += 256) wl[i] = w[i];
    __syncthreads();
    int idx = blockIdx.x * 256 + tid;
    int node = idx >> 6, j = idx & 63;
    if (node >= n) return;
    float acc = bias[j];
    const float* row = nf + node * F_NODE;
#pragma unroll
    for (int k = 0; k < F_NODE; k++) acc += row[k] * wl[k * HH + j];
    h[idx] = acc;
}

// Fused edge kernel for one conv layer:
//   z = [h[src], h[dst], ef]; m = sigmoid(z@gw+gb) * softplus(z@cw+cb);
//   atomicAdd agg[src] += m
// Block = 256 threads = 4 waves; each wave handles 4 edges per tile (16/tile).
// Both weight matrices (138x64 each) staged once per block in LDS.
__global__ __launch_bounds__(256, 2)
void edge_conv_kernel(const float* __restrict__ h,
                      const int* __restrict__ src,
                      const int* __restrict__ dst,
                      const float* __restrict__ ef,
                      const float* __restrict__ gw, const float* __restrict__ gb,
                      const float* __restrict__ cw, const float* __restrict__ cb,
                      float* __restrict__ agg, int ntiles) {
    __shared__ float gwl[IN_DIM * HH];
    __shared__ float cwl[IN_DIM * HH];
    __shared__ float zt[16 * ZROW];

    int tid = threadIdx.x;
    // stage weights (float4, both 16B-aligned: layer stride 138*64*4 bytes)
    {
        const float4* gw4 = (const float4*)gw;
        const float4* cw4 = (const float4*)cw;
        float4* gl4 = (float4*)gwl;
        float4* cl4 = (float4*)cwl;
        for (int i = tid; i < IN_DIM * HH / 4; i += 256) {
            gl4[i] = gw4[i];
            cl4[i] = cw4[i];
        }
    }
    __syncthreads();

    int lane = tid & 63;
    int w = tid >> 6;  // wave id 0..3
    float gbias = gb[lane];
    float cbias = cb[lane];

    for (int tile = blockIdx.x; tile < ntiles; tile += gridDim.x) {
        int ebase = tile * 16 + w * 4;
        int s0, s1, s2, s3;
        // stage z rows for this wave's 4 edges
#pragma unroll
        for (int e = 0; e < 4; e++) {
            int eg = ebase + e;
            int s = src[eg];
            int d = dst[eg];
            if (e == 0) s0 = s; else if (e == 1) s1 = s; else if (e == 2) s2 = s; else s3 = s;
            float* zrow = &zt[(w * 4 + e) * ZROW];
            zrow[lane] = h[s * HH + lane];
            zrow[64 + lane] = h[d * HH + lane];
            if (lane < F_EDGE) zrow[128 + lane] = ef[eg * F_EDGE + lane];
        }
        __syncthreads();

        float ag0 = 0, ag1 = 0, ag2 = 0, ag3 = 0;
        float ac0 = 0, ac1 = 0, ac2 = 0, ac3 = 0;
        const float* z0 = &zt[(w * 4 + 0) * ZROW];
        const float* z1 = &zt[(w * 4 + 1) * ZROW];
        const float* z2 = &zt[(w * 4 + 2) * ZROW];
        const float* z3 = &zt[(w * 4 + 3) * ZROW];
#pragma unroll 6
        for (int k = 0; k < IN_DIM; k++) {
            float wg = gwl[k * HH + lane];
            float wc = cwl[k * HH + lane];
            float a0 = z0[k], a1 = z1[k], a2 = z2[k], a3 = z3[k];
            ag0 += a0 * wg; ac0 += a0 * wc;
            ag1 += a1 * wg; ac1 += a1 * wc;
            ag2 += a2 * wg; ac2 += a2 * wc;
            ag3 += a3 * wg; ac3 += a3 * wc;
        }
        // activation + scatter
        {
            float m0 = sigmoid_f(ag0 + gbias) * softplus_f(ac0 + cbias);
            atomicAdd(&agg[s0 * HH + lane], m0);
            float m1 = sigmoid_f(ag1 + gbias) * softplus_f(ac1 + cbias);
            atomicAdd(&agg[s1 * HH + lane], m1);
            float m2 = sigmoid_f(ag2 + gbias) * softplus_f(ac2 + cbias);
            atomicAdd(&agg[s2 * HH + lane], m2);
            float m3 = sigmoid_f(ag3 + gbias) * softplus_f(ac3 + cbias);
            atomicAdd(&agg[s3 * HH + lane], m3);
        }
        __syncthreads();
    }
}

// per-feature sum and sum-of-squares of agg[N,64] into stats[0:64], stats[64:128]
__global__ __launch_bounds__(256)
void bn_stats_kernel(const float* __restrict__ agg, float* __restrict__ stats, int total) {
    __shared__ float ls[256], lss[256];
    int tid = threadIdx.x;
    float s = 0.f, ss = 0.f;
    // stride = gridDim*256 is a multiple of 64 -> each thread sticks to one feature
    for (int idx = blockIdx.x * 256 + tid; idx < total; idx += gridDim.x * 256) {
        float v = agg[idx];
        s += v;
        ss += v * v;
    }
    ls[tid] = s;
    lss[tid] = ss;
    __syncthreads();
    if (tid < 64) {
        s = ls[tid] + ls[tid + 64] + ls[tid + 128] + ls[tid + 192];
        ss = lss[tid] + lss[tid + 64] + lss[tid + 128] + lss[tid + 192];
        atomicAdd(&stats[tid], s);
        atomicAdd(&stats[64 + tid], ss);
    }
}

// h = softplus(h + (agg - mu)*rsqrt(var+eps)*gamma + beta)
__global__ __launch_bounds__(256)
void bn_update_kernel(float* __restrict__ h, const float* __restrict__ agg,
                      const float* __restrict__ stats,
                      const float* __restrict__ g, const float* __restrict__ b,
                      int total, float invN) {
    int idx = blockIdx.x * 256 + threadIdx.x;
    if (idx >= total) return;
    int j = idx & 63;
    float mu = stats[j] * invN;
    float var = stats[64 + j] * invN - mu * mu;
    var = fmaxf(var, 0.0f);
    float scale = g[j] * rsqrtf(var + EPSBN);
    float v = h[idx] + (agg[idx] - mu) * scale + b[j];
    h[idx] = softplus_f(v);
}

__global__ __launch_bounds__(256)
void pool_kernel(const float* __restrict__ h, const int* __restrict__ gi,
                 float* __restrict__ pool, float* __restrict__ counts, int n) {
    int idx = blockIdx.x * 256 + threadIdx.x;
    if (idx >= n * 64) return;
    int node = idx >> 6, j = idx & 63;
    int g = gi[node];
    atomicAdd(&pool[g * 64 + j], h[idx]);
    if (j == 0) atomicAdd(&counts[g], 1.0f);
}

__global__ __launch_bounds__(128)
void mlp_kernel(const float* __restrict__ pool, const float* __restrict__ counts,
                const float* __restrict__ w1, const float* __restrict__ b1,
                const float* __restrict__ w2, const float* __restrict__ b2,
                const float* __restrict__ w3, const float* __restrict__ b3,
                float* __restrict__ out) {
    __shared__ float x0[64], x1[128], x2[64];
    int b = blockIdx.x, t = threadIdx.x;
    if (t < 64) {
        float c = counts[b];
        c = c < 1.f ? 1.f : c;
        x0[t] = pool[b * 64 + t] / c;
    }
    __syncthreads();
    {
        float acc = 0.f;
#pragma unroll
        for (int k = 0; k < 64; k++) acc += x0[k] * w1[k * 128 + t];
        x1[t] = softplus_f(acc + b1[t]);
    }
    __syncthreads();
    if (t < 64) {
        float acc = 0.f;
#pragma unroll
        for (int k = 0; k < 128; k++) acc += x1[k] * w2[k * 64 + t];
        x2[t] = softplus_f(acc + b2[t]);
    }
    __syncthreads();
    if (t == 0) {
        float acc = 0.f;
        for (int k = 0; k < 64; k++) acc += x2[k] * w3[k];
        out[b] = acc + b3[0];
    }
}

extern "C" void kernel_launch(void* const* d_in, const int* in_sizes, int n_in,
                              void* d_out, int out_size, void* d_ws, size_t ws_size,
                              hipStream_t stream) {
    const float* nf      = (const float*)d_in[0];
    const int*   ei      = (const int*)d_in[1];     // [2,E]
    const float* ef      = (const float*)d_in[2];
    const int*   gi      = (const int*)d_in[3];
    const float* embed_w = (const float*)d_in[4];
    const float* embed_b = (const float*)d_in[5];
    const float* gate_w  = (const float*)d_in[6];   // [3,138,64]
    const float* gate_b  = (const float*)d_in[7];   // [3,64]
    const float* cand_w  = (const float*)d_in[8];
    const float* cand_b  = (const float*)d_in[9];
    const float* bn_g    = (const float*)d_in[10];
    const float* bn_b    = (const float*)d_in[11];
    const float* w1      = (const float*)d_in[12];
    const float* b1      = (const float*)d_in[13];
    const float* w2      = (const float*)d_in[14];
    const float* b2      = (const float*)d_in[15];
    const float* w3      = (const float*)d_in[16];
    const float* b3      = (const float*)d_in[17];
    float* out = (float*)d_out;

    float* ws = (float*)d_ws;
    const int NH = NN * HH;                 // 6,400,000
    float* h      = ws;
    float* agg    = ws + NH;
    float* stats  = ws + 2 * NH;            // 128 floats
    float* pool   = ws + 2 * NH + 128;      // 16384 floats
    float* counts = ws + 2 * NH + 128 + BB * HH;  // 256 floats

    const int* src = ei;
    const int* dst = ei + EE;

    // 1) embed
    embed_kernel<<<NH / 256, 256, 0, stream>>>(nf, embed_w, embed_b, h, NN);

    // 2) conv layers
    const int ntiles = EE / 16;
    for (int i = 0; i < N_CONV; i++) {
        hipMemsetAsync(agg, 0, (size_t)(NH + 128) * sizeof(float), stream);  // agg+stats
        edge_conv_kernel<<<512, 256, 0, stream>>>(
            h, src, dst, ef,
            gate_w + i * IN_DIM * HH, gate_b + i * HH,
            cand_w + i * IN_DIM * HH, cand_b + i * HH,
            agg, ntiles);
        bn_stats_kernel<<<512, 256, 0, stream>>>(agg, stats, NH);
        bn_update_kernel<<<NH / 256, 256, 0, stream>>>(
            h, agg, stats, bn_g + i * HH, bn_b + i * HH, NH, 1.0f / (float)NN);
    }

    // 3) pool + MLP
    hipMemsetAsync(pool, 0, (size_t)(BB * HH + BB) * sizeof(float), stream);  // pool+counts
    pool_kernel<<<NH / 256, 256, 0, stream>>>(h, gi, pool, counts, NN);
    mlp_kernel<<<BB, 128, 0, stream>>>(pool, counts, w1, b1, w2, b2, w3, b3, out);
}

// Round 2
// 2203.090 us; speedup vs baseline: 3.1152x; 3.1152x over previous
//
#include <hip/hip_runtime.h>
#include <hip/hip_bf16.h>

// Problem constants (from reference)
#define NN 100000
#define EE 1600000
#define BB 256
#define F_NODE 35
#define F_EDGE 10
#define HH 64
#define IN_DIM 138          // 2*H + F_EDGE
#define KPAD 160            // K padded to 5*32 for mfma 16x16x32
#define ZSTR 168            // LDS row stride in halves: bank step 20 mod 32 -> conflict-free
#define N_CONV 3
#define EPSBN 1e-5f

typedef _Float16 half8 __attribute__((ext_vector_type(8)));
typedef _Float16 half4v __attribute__((ext_vector_type(4)));
typedef float floatx4 __attribute__((ext_vector_type(4)));

__device__ __forceinline__ float softplus_f(float x) {
    if (x > 20.0f) return x;
    return log1pf(__expf(x));
}

__device__ __forceinline__ float sigmoid_f(float x) {
    return 1.0f / (1.0f + __expf(-x));
}

// h[N,64] = nf[N,35] @ W[35,64] + b
__global__ __launch_bounds__(256)
void embed_kernel(const float* __restrict__ nf, const float* __restrict__ w,
                  const float* __restrict__ bias, float* __restrict__ h, int n) {
    __shared__ float wl[F_NODE * HH];
    int tid = threadIdx.x;
    for (int i = tid; i < F_NODE * HH; i += 256) wl[i] = w[i];
    __syncthreads();
    int idx = blockIdx.x * 256 + tid;
    int node = idx >> 6, j = idx & 63;
    if (node >= n) return;
    float acc = bias[j];
    const float* row = nf + node * F_NODE;
#pragma unroll
    for (int k = 0; k < F_NODE; k++) acc += row[k] * wl[k * HH + j];
    h[idx] = acc;
}

// MFMA edge conv: per 64-edge block tile,
//   z = [h[src], h[dst], ef] (f16, K padded to 160)
//   [g|c] = z @ [gw|cw]^T(staged as wT[n][k])    via mfma_f32_16x16x32_f16
//   m = sigmoid(g+gb)*softplus(c+cb); atomicAdd agg[src] += m
// Block = 256 thr = 4 waves; wave handles 16 edges x 128 cols (8 C-tiles).
__global__ __launch_bounds__(256, 2)
void edge_conv_mfma(const float* __restrict__ h,
                    const int* __restrict__ src,
                    const int* __restrict__ dst,
                    const float* __restrict__ ef,
                    const float* __restrict__ gw, const float* __restrict__ gb,
                    const float* __restrict__ cw, const float* __restrict__ cb,
                    float* __restrict__ agg, int ntiles) {
    __shared__ _Float16 wT[128 * ZSTR];   // 43008 B  (n: 0-63 gate, 64-127 cand)
    __shared__ _Float16 zt[64 * ZSTR];    // 21504 B
    __shared__ int ssrc[64];

    int tid = threadIdx.x;

    // zero-init both LDS arrays (pad regions must be 0; rest overwritten)
    {
        float4* p = (float4*)wT;
        const int tot = (128 * ZSTR + 64 * ZSTR) * 2 / 16;  // zt follows wT? not guaranteed
        (void)tot;
        for (int i = tid; i < 128 * ZSTR / 8; i += 256) {
            float4 z4 = {0.f, 0.f, 0.f, 0.f};
            p[i] = z4;
        }
        float4* q = (float4*)zt;
        for (int i = tid; i < 64 * ZSTR / 8; i += 256) {
            float4 z4 = {0.f, 0.f, 0.f, 0.f};
            q[i] = z4;
        }
    }
    __syncthreads();

    // stage weights transposed: wT[n][k] = w[k][n], f16
    for (int idx = tid; idx < IN_DIM * HH; idx += 256) {
        int k = idx >> 6;       // 0..137
        int n = idx & 63;
        wT[n * ZSTR + k]        = (_Float16)gw[idx];
        wT[(64 + n) * ZSTR + k] = (_Float16)cw[idx];
    }

    int lane = tid & 63;
    int w = tid >> 6;          // wave 0..3
    int quad = lane >> 4;
    int n15 = lane & 15;

    float gbias[4], cbias[4];
#pragma unroll
    for (int t = 0; t < 4; t++) {
        gbias[t] = gb[t * 16 + n15];
        cbias[t] = cb[t * 16 + n15];
    }

    int e_loc = tid >> 2;      // 0..63: edge staged by this thread-quartet
    int qq = tid & 3;

    const _Float16* za = &zt[(w * 16 + n15) * ZSTR + quad * 8];

    for (int tile = blockIdx.x; tile < ntiles; tile += gridDim.x) {
        __syncthreads();  // previous tile's compute done before restaging zt

        // ---- stage z (f16) ----
        {
            int eg = tile * 64 + e_loc;
            int s = src[eg], d = dst[eg];
            if (qq == 0) ssrc[e_loc] = s;
            const float4* hs4 = (const float4*)(h + (size_t)s * HH);
            const float4* hd4 = (const float4*)(h + (size_t)d * HH);
            _Float16* zrow = &zt[e_loc * ZSTR];
#pragma unroll
            for (int rep = 0; rep < 4; rep++) {
                float4 v = hs4[rep * 4 + qq];
                half4v hv = {(_Float16)v.x, (_Float16)v.y, (_Float16)v.z, (_Float16)v.w};
                *(half4v*)&zrow[rep * 16 + qq * 4] = hv;
                float4 u = hd4[rep * 4 + qq];
                half4v hu = {(_Float16)u.x, (_Float16)u.y, (_Float16)u.z, (_Float16)u.w};
                *(half4v*)&zrow[64 + rep * 16 + qq * 4] = hu;
            }
            const float2* ef2 = (const float2*)(ef + (size_t)eg * F_EDGE);
            if (qq < 2) {
                float2 a = ef2[qq * 2], b = ef2[qq * 2 + 1];
                half4v hv = {(_Float16)a.x, (_Float16)a.y, (_Float16)b.x, (_Float16)b.y};
                *(half4v*)&zrow[128 + qq * 4] = hv;
            } else if (qq == 2) {
                float2 a = ef2[4];
                zrow[136] = (_Float16)a.x;
                zrow[137] = (_Float16)a.y;
            }
        }
        __syncthreads();

        // ---- MFMA: 16 edges x 128 cols per wave ----
        floatx4 acc[8];
#pragma unroll
        for (int t = 0; t < 8; t++) acc[t] = (floatx4){0.f, 0.f, 0.f, 0.f};

#pragma unroll
        for (int ks = 0; ks < 5; ks++) {
            half8 af = *(const half8*)(za + ks * 32);
#pragma unroll
            for (int t = 0; t < 8; t++) {
                half8 bf = *(const half8*)&wT[(t * 16 + n15) * ZSTR + quad * 8 + ks * 32];
                acc[t] = __builtin_amdgcn_mfma_f32_16x16x32_f16(af, bf, acc[t], 0, 0, 0);
            }
        }

        // ---- epilogue: activation + scatter ----
#pragma unroll
        for (int r = 0; r < 4; r++) {
            int s = ssrc[w * 16 + quad * 4 + r];
            float* arow = agg + (size_t)s * HH + n15;
#pragma unroll
            for (int t = 0; t < 4; t++) {
                float g = acc[t][r] + gbias[t];
                float c = acc[t + 4][r] + cbias[t];
                float m = sigmoid_f(g) * softplus_f(c);
                atomicAdd(arow + t * 16, m);
            }
        }
    }
}

// per-feature sum and sum-of-squares of agg[N,64] into stats[0:64], stats[64:128]
__global__ __launch_bounds__(256)
void bn_stats_kernel(const float* __restrict__ agg, float* __restrict__ stats, int total) {
    __shared__ float ls[256], lss[256];
    int tid = threadIdx.x;
    float s = 0.f, ss = 0.f;
    for (int idx = blockIdx.x * 256 + tid; idx < total; idx += gridDim.x * 256) {
        float v = agg[idx];
        s += v;
        ss += v * v;
    }
    ls[tid] = s;
    lss[tid] = ss;
    __syncthreads();
    if (tid < 64) {
        s = ls[tid] + ls[tid + 64] + ls[tid + 128] + ls[tid + 192];
        ss = lss[tid] + lss[tid + 64] + lss[tid + 128] + lss[tid + 192];
        atomicAdd(&stats[tid], s);
        atomicAdd(&stats[64 + tid], ss);
    }
}

// h = softplus(h + (agg - mu)*rsqrt(var+eps)*gamma + beta)
__global__ __launch_bounds__(256)
void bn_update_kernel(float* __restrict__ h, const float* __restrict__ agg,
                      const float* __restrict__ stats,
                      const float* __restrict__ g, const float* __restrict__ b,
                      int total, float invN) {
    int idx = blockIdx.x * 256 + threadIdx.x;
    if (idx >= total) return;
    int j = idx & 63;
    float mu = stats[j] * invN;
    float var = stats[64 + j] * invN - mu * mu;
    var = fmaxf(var, 0.0f);
    float scale = g[j] * rsqrtf(var + EPSBN);
    float v = h[idx] + (agg[idx] - mu) * scale + b[j];
    h[idx] = softplus_f(v);
}

__global__ __launch_bounds__(256)
void pool_kernel(const float* __restrict__ h, const int* __restrict__ gi,
                 float* __restrict__ pool, float* __restrict__ counts, int n) {
    int idx = blockIdx.x * 256 + threadIdx.x;
    if (idx >= n * 64) return;
    int node = idx >> 6, j = idx & 63;
    int g = gi[node];
    atomicAdd(&pool[g * 64 + j], h[idx]);
    if (j == 0) atomicAdd(&counts[g], 1.0f);
}

__global__ __launch_bounds__(128)
void mlp_kernel(const float* __restrict__ pool, const float* __restrict__ counts,
                const float* __restrict__ w1, const float* __restrict__ b1,
                const float* __restrict__ w2, const float* __restrict__ b2,
                const float* __restrict__ w3, const float* __restrict__ b3,
                float* __restrict__ out) {
    __shared__ float x0[64], x1[128], x2[64];
    int b = blockIdx.x, t = threadIdx.x;
    if (t < 64) {
        float c = counts[b];
        c = c < 1.f ? 1.f : c;
        x0[t] = pool[b * 64 + t] / c;
    }
    __syncthreads();
    {
        float acc = 0.f;
#pragma unroll
        for (int k = 0; k < 64; k++) acc += x0[k] * w1[k * 128 + t];
        x1[t] = softplus_f(acc + b1[t]);
    }
    __syncthreads();
    if (t < 64) {
        float acc = 0.f;
#pragma unroll
        for (int k = 0; k < 128; k++) acc += x1[k] * w2[k * 64 + t];
        x2[t] = softplus_f(acc + b2[t]);
    }
    __syncthreads();
    if (t == 0) {
        float acc = 0.f;
        for (int k = 0; k < 64; k++) acc += x2[k] * w3[k];
        out[b] = acc + b3[0];
    }
}

extern "C" void kernel_launch(void* const* d_in, const int* in_sizes, int n_in,
                              void* d_out, int out_size, void* d_ws, size_t ws_size,
                              hipStream_t stream) {
    const float* nf      = (const float*)d_in[0];
    const int*   ei      = (const int*)d_in[1];     // [2,E]
    const float* ef      = (const float*)d_in[2];
    const int*   gi      = (const int*)d_in[3];
    const float* embed_w = (const float*)d_in[4];
    const float* embed_b = (const float*)d_in[5];
    const float* gate_w  = (const float*)d_in[6];   // [3,138,64]
    const float* gate_b  = (const float*)d_in[7];   // [3,64]
    const float* cand_w  = (const float*)d_in[8];
    const float* cand_b  = (const float*)d_in[9];
    const float* bn_g    = (const float*)d_in[10];
    const float* bn_b    = (const float*)d_in[11];
    const float* w1      = (const float*)d_in[12];
    const float* b1      = (const float*)d_in[13];
    const float* w2      = (const float*)d_in[14];
    const float* b2      = (const float*)d_in[15];
    const float* w3      = (const float*)d_in[16];
    const float* b3      = (const float*)d_in[17];
    float* out = (float*)d_out;

    float* ws = (float*)d_ws;
    const int NH = NN * HH;                 // 6,400,000
    float* h      = ws;
    float* agg    = ws + NH;
    float* stats  = ws + 2 * NH;            // 128 floats
    float* pool   = ws + 2 * NH + 128;      // 16384 floats
    float* counts = ws + 2 * NH + 128 + BB * HH;  // 256 floats

    const int* src = ei;
    const int* dst = ei + EE;

    // 1) embed
    embed_kernel<<<NH / 256, 256, 0, stream>>>(nf, embed_w, embed_b, h, NN);

    // 2) conv layers
    const int ntiles = EE / 64;  // 25000
    for (int i = 0; i < N_CONV; i++) {
        hipMemsetAsync(agg, 0, (size_t)(NH + 128) * sizeof(float), stream);  // agg+stats
        edge_conv_mfma<<<512, 256, 0, stream>>>(
            h, src, dst, ef,
            gate_w + i * IN_DIM * HH, gate_b + i * HH,
            cand_w + i * IN_DIM * HH, cand_b + i * HH,
            agg, ntiles);
        bn_stats_kernel<<<512, 256, 0, stream>>>(agg, stats, NH);
        bn_update_kernel<<<NH / 256, 256, 0, stream>>>(
            h, agg, stats, bn_g + i * HH, bn_b + i * HH, NH, 1.0f / (float)NN);
    }

    // 3) pool + MLP
    hipMemsetAsync(pool, 0, (size_t)(BB * HH + BB) * sizeof(float), stream);  // pool+counts
    pool_kernel<<<NH / 256, 256, 0, stream>>>(h, gi, pool, counts, NN);
    mlp_kernel<<<BB, 128, 0, stream>>>(pool, counts, w1, b1, w2, b2, w3, b3, out);
}

// Round 3
// 1744.345 us; speedup vs baseline: 3.9344x; 1.2630x over previous
//
#include <hip/hip_runtime.h>
#include <hip/hip_bf16.h>

#define NN 100000
#define EE 1600000
#define BB 256
#define F_NODE 35
#define F_EDGE 10
#define HH 64
#define IN_DIM 138
#define ZSTR 168            // LDS row stride in halves
#define N_CONV 3
#define EPSBN 1e-5f
#define NTILES (EE / 64)    // 25000
#define NB1 ((NN + 255) / 256)  // 391 scan blocks

typedef _Float16 half8 __attribute__((ext_vector_type(8)));
typedef float floatx4 __attribute__((ext_vector_type(4)));

__device__ __forceinline__ float softplus_fast(float x) {
    // max(x,0) + log(1+exp(-|x|)); abs error ~1e-7, fine vs f16 noise
    return fmaxf(x, 0.0f) + __logf(1.0f + __expf(-fabsf(x)));
}
__device__ __forceinline__ float sigmoid_fast(float x) {
    return __builtin_amdgcn_rcpf(1.0f + __expf(-x));
}

// ---------------- edge sort by src (counting sort) ----------------
__global__ __launch_bounds__(256)
void hist_kernel(const int* __restrict__ src, int* __restrict__ cnt) {
    int e = blockIdx.x * 256 + threadIdx.x;
    atomicAdd(&cnt[src[e]], 1);
}

__global__ __launch_bounds__(256)
void scan1_kernel(int* __restrict__ cnt, int* __restrict__ bsum, int n) {
    __shared__ int ls[256];
    int t = threadIdx.x;
    int i = blockIdx.x * 256 + t;
    int v = (i < n) ? cnt[i] : 0;
    ls[t] = v;
    __syncthreads();
#pragma unroll
    for (int off = 1; off < 256; off <<= 1) {
        int add = (t >= off) ? ls[t - off] : 0;
        __syncthreads();
        ls[t] += add;
        __syncthreads();
    }
    if (i < n) cnt[i] = ls[t] - v;            // exclusive within block
    if (t == 255) bsum[blockIdx.x] = ls[255]; // block total
}

__global__ __launch_bounds__(512)
void scan2_kernel(int* __restrict__ bsum, int nb) {
    __shared__ int ls[512];
    int t = threadIdx.x;
    int v = (t < nb) ? bsum[t] : 0;
    ls[t] = v;
    __syncthreads();
#pragma unroll
    for (int off = 1; off < 512; off <<= 1) {
        int add = (t >= off) ? ls[t - off] : 0;
        __syncthreads();
        ls[t] += add;
        __syncthreads();
    }
    if (t < nb) bsum[t] = ls[t] - v;          // exclusive
}

__global__ __launch_bounds__(256)
void scan3_kernel(int* __restrict__ cnt, const int* __restrict__ bsum, int n) {
    int i = blockIdx.x * 256 + threadIdx.x;
    if (i < n) cnt[i] += bsum[blockIdx.x];
}

// permute edges into src-sorted order; convert ef to f16
__global__ __launch_bounds__(256)
void scatter_kernel(const int* __restrict__ src, const int* __restrict__ dst,
                    const float* __restrict__ ef,
                    int* __restrict__ offs,
                    int* __restrict__ ssorted, int* __restrict__ dsorted,
                    _Float16* __restrict__ ef16) {
    int e = blockIdx.x * 256 + threadIdx.x;
    int s = src[e];
    int pos = atomicAdd(&offs[s], 1);
    ssorted[pos] = s;
    dsorted[pos] = dst[e];
    const float* efe = ef + (size_t)e * F_EDGE;
    uint* op = (uint*)(ef16 + (size_t)pos * F_EDGE);  // pos*20 B, 4B aligned
#pragma unroll
    for (int i = 0; i < 5; i++) {
        _Float16 h0 = (_Float16)efe[2 * i];
        _Float16 h1 = (_Float16)efe[2 * i + 1];
        uint u = (uint)*(unsigned short*)&h0 | ((uint)*(unsigned short*)&h1 << 16);
        op[i] = u;
    }
}

// ---------------- embed: h = nf @ W + b (also writes h16) ----------------
__global__ __launch_bounds__(256)
void embed_kernel(const float* __restrict__ nf, const float* __restrict__ w,
                  const float* __restrict__ bias, float* __restrict__ h,
                  _Float16* __restrict__ h16, int n) {
    __shared__ float wl[F_NODE * HH];
    int tid = threadIdx.x;
    for (int i = tid; i < F_NODE * HH; i += 256) wl[i] = w[i];
    __syncthreads();
    int idx = blockIdx.x * 256 + tid;
    int node = idx >> 6, j = idx & 63;
    if (node >= n) return;
    float acc = bias[j];
    const float* row = nf + node * F_NODE;
#pragma unroll
    for (int k = 0; k < F_NODE; k++) acc += row[k] * wl[k * HH + j];
    h[idx] = acc;
    h16[idx] = (_Float16)acc;
}

// ---------------- MFMA edge conv over sorted edges ----------------
__global__ __launch_bounds__(256, 2)
void edge_conv_mfma(const _Float16* __restrict__ h16,
                    const int* __restrict__ esrc,
                    const int* __restrict__ edst,
                    const _Float16* __restrict__ ef16,
                    const float* __restrict__ gw, const float* __restrict__ gb,
                    const float* __restrict__ cw, const float* __restrict__ cb,
                    float* __restrict__ agg, int chunk) {
    __shared__ _Float16 wT[128 * ZSTR];   // rows 0-63 gate, 64-127 cand, cols k
    __shared__ _Float16 zt[64 * ZSTR];
    __shared__ int ssrc[64];

    int tid = threadIdx.x;
    // zero LDS (pad cols [138,160) must be 0 for MFMA)
    {
        float4 z4 = {0.f, 0.f, 0.f, 0.f};
        float4* p = (float4*)wT;
        for (int i = tid; i < 128 * ZSTR / 8; i += 256) p[i] = z4;
        float4* q = (float4*)zt;
        for (int i = tid; i < 64 * ZSTR / 8; i += 256) q[i] = z4;
    }
    __syncthreads();
    // stage weights transposed to f16: wT[n][k] = w[k][n]
    for (int idx = tid; idx < IN_DIM * HH; idx += 256) {
        int k = idx >> 6, n = idx & 63;
        wT[n * ZSTR + k]        = (_Float16)gw[idx];
        wT[(64 + n) * ZSTR + k] = (_Float16)cw[idx];
    }

    int lane = tid & 63;
    int w = tid >> 6;
    int quad = lane >> 4;
    int n15 = lane & 15;

    float gbias[4], cbias[4];
#pragma unroll
    for (int t = 0; t < 4; t++) {
        gbias[t] = gb[t * 16 + n15];
        cbias[t] = cb[t * 16 + n15];
    }

    int e_loc = tid >> 2;   // edge-in-tile staged by this quartet
    int qq = tid & 3;

    const _Float16* za = &zt[(w * 16 + n15) * ZSTR + quad * 8];

    int tile0 = blockIdx.x * chunk;
    int tile1 = tile0 + chunk;
    if (tile1 > NTILES) tile1 = NTILES;

    for (int tile = tile0; tile < tile1; ++tile) {
        __syncthreads();  // prev compute done before restaging

        // ---- stage z rows (pure f16 copies) ----
        {
            int eg = tile * 64 + e_loc;
            int s = esrc[eg], d = edst[eg];
            if (qq == 0) ssrc[e_loc] = s;
            const uint4* hs = (const uint4*)(h16 + (size_t)s * HH);
            const uint4* hd = (const uint4*)(h16 + (size_t)d * HH);
            _Float16* zrow = &zt[e_loc * ZSTR];   // byte base e_loc*336, 16B aligned
            *(uint4*)(zrow + qq * 8)            = hs[qq];
            *(uint4*)(zrow + (qq + 4) * 8)      = hs[qq + 4];
            *(uint4*)(zrow + 64 + qq * 8)       = hd[qq];
            *(uint4*)(zrow + 64 + (qq + 4) * 8) = hd[qq + 4];
            const uint* ep = (const uint*)(ef16 + (size_t)eg * F_EDGE);
            uint* zp = (uint*)(zrow + 128);
            if (qq == 0) { zp[0] = ep[0]; zp[1] = ep[1]; zp[2] = ep[2]; }
            else if (qq == 1) { zp[3] = ep[3]; zp[4] = ep[4]; }
        }
        __syncthreads();

        // ---- MFMA: 16 edges x 128 cols per wave ----
        floatx4 acc[8];
#pragma unroll
        for (int t = 0; t < 8; t++) acc[t] = (floatx4){0.f, 0.f, 0.f, 0.f};
#pragma unroll
        for (int ks = 0; ks < 5; ks++) {
            half8 af = *(const half8*)(za + ks * 32);
#pragma unroll
            for (int t = 0; t < 8; t++) {
                half8 bf = *(const half8*)&wT[(t * 16 + n15) * ZSTR + quad * 8 + ks * 32];
                acc[t] = __builtin_amdgcn_mfma_f32_16x16x32_f16(af, bf, acc[t], 0, 0, 0);
            }
        }

        // ---- epilogue: fast activation + run-merged scatter ----
        int be = w * 16 + quad * 4;
        int sprev = ssrc[be];
        float am[4];
#pragma unroll
        for (int t = 0; t < 4; t++) {
            float g = acc[t][0] + gbias[t];
            float c = acc[t + 4][0] + cbias[t];
            am[t] = sigmoid_fast(g) * softplus_fast(c);
        }
#pragma unroll
        for (int r = 1; r < 4; r++) {
            int sr = ssrc[be + r];
            float mv[4];
#pragma unroll
            for (int t = 0; t < 4; t++) {
                float g = acc[t][r] + gbias[t];
                float c = acc[t + 4][r] + cbias[t];
                mv[t] = sigmoid_fast(g) * softplus_fast(c);
            }
            if (sr == sprev) {
#pragma unroll
                for (int t = 0; t < 4; t++) am[t] += mv[t];
            } else {
                float* arow = agg + (size_t)sprev * HH + n15;
#pragma unroll
                for (int t = 0; t < 4; t++) atomicAdd(arow + t * 16, am[t]);
                sprev = sr;
#pragma unroll
                for (int t = 0; t < 4; t++) am[t] = mv[t];
            }
        }
        {
            float* arow = agg + (size_t)sprev * HH + n15;
#pragma unroll
            for (int t = 0; t < 4; t++) atomicAdd(arow + t * 16, am[t]);
        }
    }
}

// ---------------- BN ----------------
__global__ __launch_bounds__(256)
void bn_stats_kernel(const float* __restrict__ agg, float* __restrict__ stats, int total) {
    __shared__ float ls[256], lss[256];
    int tid = threadIdx.x;
    float s = 0.f, ss = 0.f;
    for (int idx = blockIdx.x * 256 + tid; idx < total; idx += gridDim.x * 256) {
        float v = agg[idx];
        s += v;
        ss += v * v;
    }
    ls[tid] = s;
    lss[tid] = ss;
    __syncthreads();
    if (tid < 64) {
        s = ls[tid] + ls[tid + 64] + ls[tid + 128] + ls[tid + 192];
        ss = lss[tid] + lss[tid + 64] + lss[tid + 128] + lss[tid + 192];
        atomicAdd(&stats[tid], s);
        atomicAdd(&stats[64 + tid], ss);
    }
}

__global__ __launch_bounds__(256)
void bn_update_kernel(float* __restrict__ h, _Float16* __restrict__ h16,
                      const float* __restrict__ agg,
                      const float* __restrict__ stats,
                      const float* __restrict__ g, const float* __restrict__ b,
                      int total, float invN) {
    int idx = blockIdx.x * 256 + threadIdx.x;
    if (idx >= total) return;
    int j = idx & 63;
    float mu = stats[j] * invN;
    float var = stats[64 + j] * invN - mu * mu;
    var = fmaxf(var, 0.0f);
    float scale = g[j] * rsqrtf(var + EPSBN);
    float v = h[idx] + (agg[idx] - mu) * scale + b[j];
    float hv = softplus_fast(v);
    h[idx] = hv;
    h16[idx] = (_Float16)hv;
}

// ---------------- pool (graph_index is sorted -> run merge) ----------------
__global__ __launch_bounds__(256)
void pool_kernel(const float* __restrict__ h, const int* __restrict__ gi,
                 float* __restrict__ pool, float* __restrict__ counts, int n) {
    int tid = threadIdx.x;
    int grp = tid >> 6;
    int j = tid & 63;
    int n0 = blockIdx.x * 64 + grp * 16;
    if (n0 >= n) return;
    int nend = n0 + 16; if (nend > n) nend = n;
    int gprev = gi[n0];
    float a = 0.f;
    int cnt = 0;
    for (int nn = n0; nn < nend; nn++) {
        int gg = gi[nn];
        if (gg != gprev) {
            atomicAdd(&pool[gprev * 64 + j], a);
            if (j == 0) atomicAdd(&counts[gprev], (float)cnt);
            a = 0.f; cnt = 0; gprev = gg;
        }
        a += h[(size_t)nn * 64 + j];
        cnt++;
    }
    atomicAdd(&pool[gprev * 64 + j], a);
    if (j == 0) atomicAdd(&counts[gprev], (float)cnt);
}

__global__ __launch_bounds__(128)
void mlp_kernel(const float* __restrict__ pool, const float* __restrict__ counts,
                const float* __restrict__ w1, const float* __restrict__ b1,
                const float* __restrict__ w2, const float* __restrict__ b2,
                const float* __restrict__ w3, const float* __restrict__ b3,
                float* __restrict__ out) {
    __shared__ float x0[64], x1[128], x2[64];
    int b = blockIdx.x, t = threadIdx.x;
    if (t < 64) {
        float c = counts[b];
        c = c < 1.f ? 1.f : c;
        x0[t] = pool[b * 64 + t] / c;
    }
    __syncthreads();
    {
        float acc = 0.f;
#pragma unroll
        for (int k = 0; k < 64; k++) acc += x0[k] * w1[k * 128 + t];
        x1[t] = softplus_fast(acc + b1[t]);
    }
    __syncthreads();
    if (t < 64) {
        float acc = 0.f;
#pragma unroll
        for (int k = 0; k < 128; k++) acc += x1[k] * w2[k * 64 + t];
        x2[t] = softplus_fast(acc + b2[t]);
    }
    __syncthreads();
    if (t == 0) {
        float acc = 0.f;
        for (int k = 0; k < 64; k++) acc += x2[k] * w3[k];
        out[b] = acc + b3[0];
    }
}

extern "C" void kernel_launch(void* const* d_in, const int* in_sizes, int n_in,
                              void* d_out, int out_size, void* d_ws, size_t ws_size,
                              hipStream_t stream) {
    const float* nf      = (const float*)d_in[0];
    const int*   ei      = (const int*)d_in[1];
    const float* ef      = (const float*)d_in[2];
    const int*   gi      = (const int*)d_in[3];
    const float* embed_w = (const float*)d_in[4];
    const float* embed_b = (const float*)d_in[5];
    const float* gate_w  = (const float*)d_in[6];
    const float* gate_b  = (const float*)d_in[7];
    const float* cand_w  = (const float*)d_in[8];
    const float* cand_b  = (const float*)d_in[9];
    const float* bn_g    = (const float*)d_in[10];
    const float* bn_b    = (const float*)d_in[11];
    const float* w1      = (const float*)d_in[12];
    const float* b1      = (const float*)d_in[13];
    const float* w2      = (const float*)d_in[14];
    const float* b2      = (const float*)d_in[15];
    const float* w3      = (const float*)d_in[16];
    const float* b3      = (const float*)d_in[17];
    float* out = (float*)d_out;

    const int NH = NN * HH;  // 6.4M
    char* p = (char*)d_ws;
    float*     h       = (float*)p;            p += (size_t)NH * 4;
    float*     agg     = (float*)p;            p += (size_t)NH * 4;
    float*     stats   = (float*)p;            p += 128 * 4;
    _Float16*  h16     = (_Float16*)p;         p += (size_t)NH * 2;
    int*       ssorted = (int*)p;              p += (size_t)EE * 4;
    int*       dsorted = (int*)p;              p += (size_t)EE * 4;
    _Float16*  ef16    = (_Float16*)p;         p += (size_t)EE * F_EDGE * 2;
    int*       offs    = (int*)p;              p += (size_t)NN * 4;
    int*       bsum    = (int*)p;              p += 512 * 4;
    float*     pool    = (float*)p;            p += (size_t)BB * HH * 4;
    float*     counts  = (float*)p;            p += (size_t)BB * 4;

    const int* src = ei;
    const int* dst = ei + EE;

    // ---- sort edges by src (once, reused by all 3 convs) ----
    hipMemsetAsync(offs, 0, (size_t)NN * 4, stream);
    hist_kernel<<<EE / 256, 256, 0, stream>>>(src, offs);
    scan1_kernel<<<NB1, 256, 0, stream>>>(offs, bsum, NN);
    scan2_kernel<<<1, 512, 0, stream>>>(bsum, NB1);
    scan3_kernel<<<NB1, 256, 0, stream>>>(offs, bsum, NN);
    scatter_kernel<<<EE / 256, 256, 0, stream>>>(src, dst, ef, offs, ssorted, dsorted, ef16);

    // ---- embed ----
    embed_kernel<<<NH / 256, 256, 0, stream>>>(nf, embed_w, embed_b, h, h16, NN);

    // ---- conv layers ----
    const int grid = 512;
    const int chunk = (NTILES + grid - 1) / grid;  // 49
    for (int i = 0; i < N_CONV; i++) {
        hipMemsetAsync(agg, 0, ((size_t)NH + 128) * 4, stream);  // agg + stats
        edge_conv_mfma<<<grid, 256, 0, stream>>>(
            h16, ssorted, dsorted, ef16,
            gate_w + i * IN_DIM * HH, gate_b + i * HH,
            cand_w + i * IN_DIM * HH, cand_b + i * HH,
            agg, chunk);
        bn_stats_kernel<<<512, 256, 0, stream>>>(agg, stats, NH);
        bn_update_kernel<<<NH / 256, 256, 0, stream>>>(
            h, h16, agg, stats, bn_g + i * HH, bn_b + i * HH, NH, 1.0f / (float)NN);
    }

    // ---- pool + MLP ----
    hipMemsetAsync(pool, 0, (size_t)(BB * HH + BB) * 4, stream);
    pool_kernel<<<(NN + 63) / 64, 256, 0, stream>>>(h, gi, pool, counts, NN);
    mlp_kernel<<<BB, 128, 0, stream>>>(pool, counts, w1, b1, w2, b2, w3, b3, out);
}

// Round 4
// 968.984 us; speedup vs baseline: 7.0827x; 1.8002x over previous
//
#include <hip/hip_runtime.h>
#include <hip/hip_bf16.h>

#define NN 100000
#define EE 1600000
#define BB 256
#define F_NODE 35
#define F_EDGE 10
#define HH 64
#define IN_DIM 138
#define N_CONV 3
#define EPSBN 1e-5f
#define NB1 ((NN + 255) / 256)  // 391 scan blocks

// conv tiling: 2000 independent waves, 800 edges each, 16 slab-groups of 4
#define NWAVES 2000
#define NGROUPS 50
#define SUBLEN 200          // 4*NGROUPS
#define EPW 800             // 16*NGROUPS
#define EFSTR 12            // padded ef row in halves (24 B)

typedef _Float16 half8 __attribute__((ext_vector_type(8)));
typedef float floatx4 __attribute__((ext_vector_type(4)));

__device__ __forceinline__ float softplus_fast(float x) {
    return fmaxf(x, 0.0f) + __logf(1.0f + __expf(-fabsf(x)));
}
__device__ __forceinline__ float sigmoid_fast(float x) {
    return __builtin_amdgcn_rcpf(1.0f + __expf(-x));
}

// ---------------- edge sort by src (counting sort) ----------------
__global__ __launch_bounds__(256)
void hist_kernel(const int* __restrict__ src, int* __restrict__ cnt) {
    int e = blockIdx.x * 256 + threadIdx.x;
    atomicAdd(&cnt[src[e]], 1);
}

__global__ __launch_bounds__(256)
void scan1_kernel(int* __restrict__ cnt, int* __restrict__ bsum, int n) {
    __shared__ int ls[256];
    int t = threadIdx.x;
    int i = blockIdx.x * 256 + t;
    int v = (i < n) ? cnt[i] : 0;
    ls[t] = v;
    __syncthreads();
#pragma unroll
    for (int off = 1; off < 256; off <<= 1) {
        int add = (t >= off) ? ls[t - off] : 0;
        __syncthreads();
        ls[t] += add;
        __syncthreads();
    }
    if (i < n) cnt[i] = ls[t] - v;
    if (t == 255) bsum[blockIdx.x] = ls[255];
}

__global__ __launch_bounds__(512)
void scan2_kernel(int* __restrict__ bsum, int nb) {
    __shared__ int ls[512];
    int t = threadIdx.x;
    int v = (t < nb) ? bsum[t] : 0;
    ls[t] = v;
    __syncthreads();
#pragma unroll
    for (int off = 1; off < 512; off <<= 1) {
        int add = (t >= off) ? ls[t - off] : 0;
        __syncthreads();
        ls[t] += add;
        __syncthreads();
    }
    if (t < nb) bsum[t] = ls[t] - v;
}

__global__ __launch_bounds__(256)
void scan3_kernel(int* __restrict__ cnt, const int* __restrict__ bsum, int n) {
    int i = blockIdx.x * 256 + threadIdx.x;
    if (i < n) cnt[i] += bsum[blockIdx.x];
}

// permute edges into src-sorted order; ef -> f16 padded to 12 halves
__global__ __launch_bounds__(256)
void scatter_kernel(const int* __restrict__ src, const int* __restrict__ dst,
                    const float* __restrict__ ef,
                    int* __restrict__ offs,
                    int* __restrict__ ssorted, int* __restrict__ dsorted,
                    _Float16* __restrict__ ef16) {
    int e = blockIdx.x * 256 + threadIdx.x;
    int s = src[e];
    int pos = atomicAdd(&offs[s], 1);
    ssorted[pos] = s;
    dsorted[pos] = dst[e];
    const float* efe = ef + (size_t)e * F_EDGE;
    uint* op = (uint*)(ef16 + (size_t)pos * EFSTR);
#pragma unroll
    for (int i = 0; i < 5; i++) {
        _Float16 h0 = (_Float16)efe[2 * i];
        _Float16 h1 = (_Float16)efe[2 * i + 1];
        op[i] = (uint)*(unsigned short*)&h0 | ((uint)*(unsigned short*)&h1 << 16);
    }
    op[5] = 0u;  // pad halves 10,11
}

// weights -> f16 transposed [layer][n=0..127][k=0..159], zero-padded K
__global__ __launch_bounds__(256)
void prep_w_kernel(const float* __restrict__ gw, const float* __restrict__ cw,
                   _Float16* __restrict__ wT) {
    int idx = blockIdx.x * 256 + threadIdx.x;
    if (idx >= 3 * 128 * 160) return;
    int k = idx % 160;
    int n = (idx / 160) & 127;
    int layer = idx / (160 * 128);
    float v = 0.f;
    if (k < IN_DIM)
        v = (n < 64) ? gw[layer * IN_DIM * HH + k * HH + n]
                     : cw[layer * IN_DIM * HH + k * HH + (n - 64)];
    wT[idx] = (_Float16)v;
}

// ---------------- embed ----------------
__global__ __launch_bounds__(256)
void embed_kernel(const float* __restrict__ nf, const float* __restrict__ w,
                  const float* __restrict__ bias, float* __restrict__ h,
                  _Float16* __restrict__ h16, int n) {
    __shared__ float wl[F_NODE * HH];
    int tid = threadIdx.x;
    for (int i = tid; i < F_NODE * HH; i += 256) wl[i] = w[i];
    __syncthreads();
    int idx = blockIdx.x * 256 + tid;
    int node = idx >> 6, j = idx & 63;
    if (node >= n) return;
    float acc = bias[j];
    const float* row = nf + node * F_NODE;
#pragma unroll
    for (int k = 0; k < F_NODE; k++) acc += row[k] * wl[k * HH + j];
    h[idx] = acc;
    h16[idx] = (_Float16)acc;
}

// ---------------- conv: barrier-free, LDS-free, B-in-registers ----------------
__device__ __forceinline__ void load_A(const _Float16* __restrict__ h16,
                                       const _Float16* __restrict__ ef16,
                                       int s, int d, int eg, int quad,
                                       uint4& A0, uint4& A1, uint4& A2, uint4& A3,
                                       uint4& A4) {
    const uint4* hs = (const uint4*)(h16 + (size_t)s * HH);
    const uint4* hd = (const uint4*)(h16 + (size_t)d * HH);
    A0 = hs[quad];
    A1 = hs[quad + 4];
    A2 = hd[quad];
    A3 = hd[quad + 4];
    uint4 z; z.x = z.y = z.z = z.w = 0u;
    A4 = z;
    const _Float16* p = ef16 + (size_t)eg * EFSTR;
    if (quad == 0) {
        uint2 a = *(const uint2*)p;
        uint2 b = *(const uint2*)(p + 4);
        A4.x = a.x; A4.y = a.y; A4.z = b.x; A4.w = b.y;
    } else if (quad == 1) {
        uint2 a = *(const uint2*)(p + 8);   // halves 8,9,0,0
        A4.x = a.x; A4.y = a.y;
    }
}

__global__ __launch_bounds__(64, 2)
void edge_conv_mfma(const _Float16* __restrict__ h16,
                    const int* __restrict__ esrc,
                    const int* __restrict__ edst,
                    const _Float16* __restrict__ ef16,
                    const _Float16* __restrict__ wT,   // [128][160] this layer
                    const float* __restrict__ gb, const float* __restrict__ cb,
                    float* __restrict__ agg) {
    int lane = threadIdx.x;
    int quad = lane >> 4, n15 = lane & 15;
    int base = blockIdx.x * EPW + ((n15 >> 2) * SUBLEN) + (n15 & 3);

    // B fragments in registers: 40 half8 = 160 VGPRs
    half8 B[8][5];
#pragma unroll
    for (int t = 0; t < 8; t++) {
        const _Float16* wr = wT + (t * 16 + n15) * 160 + quad * 8;
#pragma unroll
        for (int ks = 0; ks < 5; ks++)
            B[t][ks] = *(const half8*)(wr + ks * 32);
    }
    float gb0 = gb[n15], gb1 = gb[16 + n15], gb2 = gb[32 + n15], gb3 = gb[48 + n15];
    float cb0 = cb[n15], cb1 = cb[16 + n15], cb2 = cb[32 + n15], cb3 = cb[48 + n15];

    int sprev = -1;
    float am0 = 0.f, am1 = 0.f, am2 = 0.f, am3 = 0.f;

    // software pipeline: A regs 1 group ahead, indices 2 groups ahead
    int eg = base;
    int s = esrc[eg], d = edst[eg];
    uint4 A0, A1, A2, A3, A4;
    load_A(h16, ef16, s, d, eg, quad, A0, A1, A2, A3, A4);
    int egn = base + 4;
    int sn = esrc[egn], dn = edst[egn];

    for (int g = 0; g < NGROUPS; g++) {
        int s_cur = s;

        floatx4 acc[8];
#pragma unroll
        for (int t = 0; t < 8; t++) acc[t] = (floatx4){0.f, 0.f, 0.f, 0.f};

        half8 a0 = __builtin_bit_cast(half8, A0);
        half8 a1 = __builtin_bit_cast(half8, A1);
        half8 a2 = __builtin_bit_cast(half8, A2);
        half8 a3 = __builtin_bit_cast(half8, A3);
        half8 a4 = __builtin_bit_cast(half8, A4);
#pragma unroll
        for (int t = 0; t < 8; t++) acc[t] = __builtin_amdgcn_mfma_f32_16x16x32_f16(a0, B[t][0], acc[t], 0, 0, 0);
#pragma unroll
        for (int t = 0; t < 8; t++) acc[t] = __builtin_amdgcn_mfma_f32_16x16x32_f16(a1, B[t][1], acc[t], 0, 0, 0);
#pragma unroll
        for (int t = 0; t < 8; t++) acc[t] = __builtin_amdgcn_mfma_f32_16x16x32_f16(a2, B[t][2], acc[t], 0, 0, 0);
#pragma unroll
        for (int t = 0; t < 8; t++) acc[t] = __builtin_amdgcn_mfma_f32_16x16x32_f16(a3, B[t][3], acc[t], 0, 0, 0);
#pragma unroll
        for (int t = 0; t < 8; t++) acc[t] = __builtin_amdgcn_mfma_f32_16x16x32_f16(a4, B[t][4], acc[t], 0, 0, 0);

        // issue next group's A gathers (overlap epilogue); clamp on last iters
        int egc = base + ((g + 1 < NGROUPS) ? (g + 1) * 4 : g * 4);
        load_A(h16, ef16, sn, dn, egc, quad, A0, A1, A2, A3, A4);
        s = sn; d = dn;
        int eg2 = base + ((g + 2 < NGROUPS) ? (g + 2) * 4 : (NGROUPS - 1) * 4);
        sn = esrc[eg2]; dn = edst[eg2];

        // epilogue: activation + full-run-merged scatter
#pragma unroll
        for (int r = 0; r < 4; r++) {
            int sr = __shfl(s_cur, quad * 4 + r, 64);
            if (sr != sprev) {
                if (sprev >= 0) {
                    float* p = agg + (size_t)sprev * HH + n15;
                    atomicAdd(p, am0);
                    atomicAdd(p + 16, am1);
                    atomicAdd(p + 32, am2);
                    atomicAdd(p + 48, am3);
                }
                sprev = sr;
                am0 = am1 = am2 = am3 = 0.f;
            }
            am0 += sigmoid_fast(acc[0][r] + gb0) * softplus_fast(acc[4][r] + cb0);
            am1 += sigmoid_fast(acc[1][r] + gb1) * softplus_fast(acc[5][r] + cb1);
            am2 += sigmoid_fast(acc[2][r] + gb2) * softplus_fast(acc[6][r] + cb2);
            am3 += sigmoid_fast(acc[3][r] + gb3) * softplus_fast(acc[7][r] + cb3);
        }
    }
    if (sprev >= 0) {
        float* p = agg + (size_t)sprev * HH + n15;
        atomicAdd(p, am0);
        atomicAdd(p + 16, am1);
        atomicAdd(p + 32, am2);
        atomicAdd(p + 48, am3);
    }
}

// ---------------- BN ----------------
__global__ __launch_bounds__(256)
void bn_stats_kernel(const float* __restrict__ agg, float* __restrict__ stats, int total) {
    __shared__ float ls[256], lss[256];
    int tid = threadIdx.x;
    float s = 0.f, ss = 0.f;
    for (int idx = blockIdx.x * 256 + tid; idx < total; idx += gridDim.x * 256) {
        float v = agg[idx];
        s += v;
        ss += v * v;
    }
    ls[tid] = s;
    lss[tid] = ss;
    __syncthreads();
    if (tid < 64) {
        s = ls[tid] + ls[tid + 64] + ls[tid + 128] + ls[tid + 192];
        ss = lss[tid] + lss[tid + 64] + lss[tid + 128] + lss[tid + 192];
        atomicAdd(&stats[tid], s);
        atomicAdd(&stats[64 + tid], ss);
    }
}

__global__ __launch_bounds__(256)
void bn_update_kernel(float* __restrict__ h, _Float16* __restrict__ h16,
                      const float* __restrict__ agg,
                      const float* __restrict__ stats,
                      const float* __restrict__ g, const float* __restrict__ b,
                      int total, float invN) {
    int idx = blockIdx.x * 256 + threadIdx.x;
    if (idx >= total) return;
    int j = idx & 63;
    float mu = stats[j] * invN;
    float var = stats[64 + j] * invN - mu * mu;
    var = fmaxf(var, 0.0f);
    float scale = g[j] * rsqrtf(var + EPSBN);
    float v = h[idx] + (agg[idx] - mu) * scale + b[j];
    float hv = softplus_fast(v);
    h[idx] = hv;
    h16[idx] = (_Float16)hv;
}

// ---------------- pool ----------------
__global__ __launch_bounds__(256)
void pool_kernel(const float* __restrict__ h, const int* __restrict__ gi,
                 float* __restrict__ pool, float* __restrict__ counts, int n) {
    int tid = threadIdx.x;
    int grp = tid >> 6;
    int j = tid & 63;
    int n0 = blockIdx.x * 64 + grp * 16;
    if (n0 >= n) return;
    int nend = n0 + 16; if (nend > n) nend = n;
    int gprev = gi[n0];
    float a = 0.f;
    int cnt = 0;
    for (int nn = n0; nn < nend; nn++) {
        int gg = gi[nn];
        if (gg != gprev) {
            atomicAdd(&pool[gprev * 64 + j], a);
            if (j == 0) atomicAdd(&counts[gprev], (float)cnt);
            a = 0.f; cnt = 0; gprev = gg;
        }
        a += h[(size_t)nn * 64 + j];
        cnt++;
    }
    atomicAdd(&pool[gprev * 64 + j], a);
    if (j == 0) atomicAdd(&counts[gprev], (float)cnt);
}

__global__ __launch_bounds__(128)
void mlp_kernel(const float* __restrict__ pool, const float* __restrict__ counts,
                const float* __restrict__ w1, const float* __restrict__ b1,
                const float* __restrict__ w2, const float* __restrict__ b2,
                const float* __restrict__ w3, const float* __restrict__ b3,
                float* __restrict__ out) {
    __shared__ float x0[64], x1[128], x2[64];
    int b = blockIdx.x, t = threadIdx.x;
    if (t < 64) {
        float c = counts[b];
        c = c < 1.f ? 1.f : c;
        x0[t] = pool[b * 64 + t] / c;
    }
    __syncthreads();
    {
        float acc = 0.f;
#pragma unroll
        for (int k = 0; k < 64; k++) acc += x0[k] * w1[k * 128 + t];
        x1[t] = softplus_fast(acc + b1[t]);
    }
    __syncthreads();
    if (t < 64) {
        float acc = 0.f;
#pragma unroll
        for (int k = 0; k < 128; k++) acc += x1[k] * w2[k * 64 + t];
        x2[t] = softplus_fast(acc + b2[t]);
    }
    __syncthreads();
    if (t == 0) {
        float acc = 0.f;
        for (int k = 0; k < 64; k++) acc += x2[k] * w3[k];
        out[b] = acc + b3[0];
    }
}

extern "C" void kernel_launch(void* const* d_in, const int* in_sizes, int n_in,
                              void* d_out, int out_size, void* d_ws, size_t ws_size,
                              hipStream_t stream) {
    const float* nf      = (const float*)d_in[0];
    const int*   ei      = (const int*)d_in[1];
    const float* ef      = (const float*)d_in[2];
    const int*   gi      = (const int*)d_in[3];
    const float* embed_w = (const float*)d_in[4];
    const float* embed_b = (const float*)d_in[5];
    const float* gate_w  = (const float*)d_in[6];
    const float* gate_b  = (const float*)d_in[7];
    const float* cand_w  = (const float*)d_in[8];
    const float* cand_b  = (const float*)d_in[9];
    const float* bn_g    = (const float*)d_in[10];
    const float* bn_b    = (const float*)d_in[11];
    const float* w1      = (const float*)d_in[12];
    const float* b1      = (const float*)d_in[13];
    const float* w2      = (const float*)d_in[14];
    const float* b2      = (const float*)d_in[15];
    const float* w3      = (const float*)d_in[16];
    const float* b3      = (const float*)d_in[17];
    float* out = (float*)d_out;

    const int NH = NN * HH;  // 6.4M
    char* p = (char*)d_ws;
    float*     h       = (float*)p;            p += (size_t)NH * 4;
    float*     agg     = (float*)p;            p += (size_t)NH * 4;
    float*     stats   = (float*)p;            p += 128 * 4;
    _Float16*  h16     = (_Float16*)p;         p += (size_t)NH * 2;
    int*       ssorted = (int*)p;              p += (size_t)EE * 4;
    int*       dsorted = (int*)p;              p += (size_t)EE * 4;
    _Float16*  ef16    = (_Float16*)p;         p += (size_t)EE * EFSTR * 2;
    _Float16*  wTall   = (_Float16*)p;         p += (size_t)3 * 128 * 160 * 2;
    int*       offs    = (int*)p;              p += (size_t)NN * 4;
    int*       bsum    = (int*)p;              p += 512 * 4;
    float*     pool    = (float*)p;            p += (size_t)BB * HH * 4;
    float*     counts  = (float*)p;            p += (size_t)BB * 4;

    const int* src = ei;
    const int* dst = ei + EE;

    // ---- sort edges by src + weight prep ----
    hipMemsetAsync(offs, 0, (size_t)NN * 4, stream);
    hist_kernel<<<EE / 256, 256, 0, stream>>>(src, offs);
    prep_w_kernel<<<(3 * 128 * 160 + 255) / 256, 256, 0, stream>>>(gate_w, cand_w, wTall);
    scan1_kernel<<<NB1, 256, 0, stream>>>(offs, bsum, NN);
    scan2_kernel<<<1, 512, 0, stream>>>(bsum, NB1);
    scan3_kernel<<<NB1, 256, 0, stream>>>(offs, bsum, NN);
    scatter_kernel<<<EE / 256, 256, 0, stream>>>(src, dst, ef, offs, ssorted, dsorted, ef16);

    // ---- embed ----
    embed_kernel<<<NH / 256, 256, 0, stream>>>(nf, embed_w, embed_b, h, h16, NN);

    // ---- conv layers ----
    for (int i = 0; i < N_CONV; i++) {
        hipMemsetAsync(agg, 0, ((size_t)NH + 128) * 4, stream);  // agg + stats
        edge_conv_mfma<<<NWAVES, 64, 0, stream>>>(
            h16, ssorted, dsorted, ef16,
            wTall + (size_t)i * 128 * 160,
            gate_b + i * HH, cand_b + i * HH, agg);
        bn_stats_kernel<<<512, 256, 0, stream>>>(agg, stats, NH);
        bn_update_kernel<<<NH / 256, 256, 0, stream>>>(
            h, h16, agg, stats, bn_g + i * HH, bn_b + i * HH, NH, 1.0f / (float)NN);
    }

    // ---- pool + MLP ----
    hipMemsetAsync(pool, 0, (size_t)(BB * HH + BB) * 4, stream);
    pool_kernel<<<(NN + 63) / 64, 256, 0, stream>>>(h, gi, pool, counts, NN);
    mlp_kernel<<<BB, 128, 0, stream>>>(pool, counts, w1, b1, w2, b2, w3, b3, out);
}

// Round 5
// 894.985 us; speedup vs baseline: 7.6683x; 1.0827x over previous
//
#include <hip/hip_runtime.h>
#include <hip/hip_bf16.h>

#define NN 100000
#define EE 1600000
#define BB 256
#define F_NODE 35
#define F_EDGE 10
#define HH 64
#define IN_DIM 138
#define N_CONV 3
#define EPSBN 1e-5f
#define NB1 ((NN + 255) / 256)  // 391 scan blocks

// conv tiling: 2000 independent waves, 800 edges each
#define NWAVES 2000
#define NGROUPS 50
#define SUBLEN 200          // 4*NGROUPS
#define EPW 800             // 16*NGROUPS
#define EFSTR 12            // padded ef row in halves (24 B)

typedef _Float16 half8 __attribute__((ext_vector_type(8)));
typedef float floatx4 __attribute__((ext_vector_type(4)));

__device__ __forceinline__ float softplus_fast(float x) {
    return fmaxf(x, 0.0f) + __logf(1.0f + __expf(-fabsf(x)));
}
__device__ __forceinline__ float sigmoid_fast(float x) {
    return __builtin_amdgcn_rcpf(1.0f + __expf(-x));
}

// ---------------- sort by src: hist+rank, scan, perm, gather ----------------
__global__ __launch_bounds__(256)
void hist_rank_kernel(const int* __restrict__ src, int* __restrict__ cnt,
                      int* __restrict__ rank) {
    int e = blockIdx.x * 256 + threadIdx.x;
    rank[e] = atomicAdd(&cnt[src[e]], 1);
}

__global__ __launch_bounds__(256)
void scan1_kernel(int* __restrict__ cnt, int* __restrict__ bsum, int n) {
    __shared__ int ls[256];
    int t = threadIdx.x;
    int i = blockIdx.x * 256 + t;
    int v = (i < n) ? cnt[i] : 0;
    ls[t] = v;
    __syncthreads();
#pragma unroll
    for (int off = 1; off < 256; off <<= 1) {
        int add = (t >= off) ? ls[t - off] : 0;
        __syncthreads();
        ls[t] += add;
        __syncthreads();
    }
    if (i < n) cnt[i] = ls[t] - v;
    if (t == 255) bsum[blockIdx.x] = ls[255];
}

__global__ __launch_bounds__(512)
void scan2_kernel(int* __restrict__ bsum, int nb) {
    __shared__ int ls[512];
    int t = threadIdx.x;
    int v = (t < nb) ? bsum[t] : 0;
    ls[t] = v;
    __syncthreads();
#pragma unroll
    for (int off = 1; off < 512; off <<= 1) {
        int add = (t >= off) ? ls[t - off] : 0;
        __syncthreads();
        ls[t] += add;
        __syncthreads();
    }
    if (t < nb) bsum[t] = ls[t] - v;
}

__global__ __launch_bounds__(256)
void scan3_kernel(int* __restrict__ cnt, const int* __restrict__ bsum, int n) {
    int i = blockIdx.x * 256 + threadIdx.x;
    if (i < n) cnt[i] += bsum[blockIdx.x];
}

// perm[offs[src[e]] + rank[e]] = e  — only 4B random writes (L2-resident perm)
__global__ __launch_bounds__(256)
void perm_kernel(const int* __restrict__ src, const int* __restrict__ rank,
                 const int* __restrict__ offs, int* __restrict__ perm) {
    int e = blockIdx.x * 256 + threadIdx.x;
    perm[offs[src[e]] + rank[e]] = e;
}

// coalesced-write gather into sorted arrays; ef -> f16 padded to 12 halves
__global__ __launch_bounds__(256)
void gather_kernel(const int* __restrict__ perm,
                   const int* __restrict__ src, const int* __restrict__ dst,
                   const float* __restrict__ ef,
                   int* __restrict__ ssorted, int* __restrict__ dsorted,
                   _Float16* __restrict__ ef16) {
    int pos = blockIdx.x * 256 + threadIdx.x;
    int e = perm[pos];
    ssorted[pos] = src[e];
    dsorted[pos] = dst[e];
    const float2* efe = (const float2*)(ef + (size_t)e * F_EDGE);
    uint* op = (uint*)(ef16 + (size_t)pos * EFSTR);
#pragma unroll
    for (int i = 0; i < 5; i++) {
        float2 v = efe[i];
        _Float16 h0 = (_Float16)v.x;
        _Float16 h1 = (_Float16)v.y;
        op[i] = (uint)*(unsigned short*)&h0 | ((uint)*(unsigned short*)&h1 << 16);
    }
    op[5] = 0u;
}

// weights -> f16 transposed [layer][n=0..127][k=0..159], zero-padded K
__global__ __launch_bounds__(256)
void prep_w_kernel(const float* __restrict__ gw, const float* __restrict__ cw,
                   _Float16* __restrict__ wT) {
    int idx = blockIdx.x * 256 + threadIdx.x;
    if (idx >= 3 * 128 * 160) return;
    int k = idx % 160;
    int n = (idx / 160) & 127;
    int layer = idx / (160 * 128);
    float v = 0.f;
    if (k < IN_DIM)
        v = (n < 64) ? gw[layer * IN_DIM * HH + k * HH + n]
                     : cw[layer * IN_DIM * HH + k * HH + (n - 64)];
    wT[idx] = (_Float16)v;
}

// ---------------- embed ----------------
__global__ __launch_bounds__(256)
void embed_kernel(const float* __restrict__ nf, const float* __restrict__ w,
                  const float* __restrict__ bias, float* __restrict__ h,
                  _Float16* __restrict__ h16, int n) {
    __shared__ float wl[F_NODE * HH];
    int tid = threadIdx.x;
    for (int i = tid; i < F_NODE * HH; i += 256) wl[i] = w[i];
    __syncthreads();
    int idx = blockIdx.x * 256 + tid;
    int node = idx >> 6, j = idx & 63;
    if (node >= n) return;
    float acc = bias[j];
    const float* row = nf + node * F_NODE;
#pragma unroll
    for (int k = 0; k < F_NODE; k++) acc += row[k] * wl[k * HH + j];
    h[idx] = acc;
    h16[idx] = (_Float16)acc;
}

// ---------------- conv: barrier-free, LDS-free, B-in-registers ----------------
__device__ __forceinline__ void load_A(const _Float16* __restrict__ h16,
                                       const _Float16* __restrict__ ef16,
                                       int s, int d, int eg, int quad,
                                       uint4& A0, uint4& A1, uint4& A2, uint4& A3,
                                       uint4& A4) {
    const uint4* hs = (const uint4*)(h16 + (size_t)s * HH);
    const uint4* hd = (const uint4*)(h16 + (size_t)d * HH);
    A0 = hs[quad];
    A1 = hs[quad + 4];
    A2 = hd[quad];
    A3 = hd[quad + 4];
    uint4 z; z.x = z.y = z.z = z.w = 0u;
    A4 = z;
    const _Float16* p = ef16 + (size_t)eg * EFSTR;
    if (quad == 0) {
        uint2 a = *(const uint2*)p;
        uint2 b = *(const uint2*)(p + 4);
        A4.x = a.x; A4.y = a.y; A4.z = b.x; A4.w = b.y;
    } else if (quad == 1) {
        uint2 a = *(const uint2*)(p + 8);
        A4.x = a.x; A4.y = a.y;
    }
}

__global__ __launch_bounds__(64, 2)
void edge_conv_mfma(const _Float16* __restrict__ h16,
                    const int* __restrict__ esrc,
                    const int* __restrict__ edst,
                    const _Float16* __restrict__ ef16,
                    const _Float16* __restrict__ wT,
                    const float* __restrict__ gb, const float* __restrict__ cb,
                    float* __restrict__ agg) {
    int lane = threadIdx.x;
    int quad = lane >> 4, n15 = lane & 15;
    int base = blockIdx.x * EPW + ((n15 >> 2) * SUBLEN) + (n15 & 3);

    half8 B[8][5];
#pragma unroll
    for (int t = 0; t < 8; t++) {
        const _Float16* wr = wT + (t * 16 + n15) * 160 + quad * 8;
#pragma unroll
        for (int ks = 0; ks < 5; ks++)
            B[t][ks] = *(const half8*)(wr + ks * 32);
    }
    float gb0 = gb[n15], gb1 = gb[16 + n15], gb2 = gb[32 + n15], gb3 = gb[48 + n15];
    float cb0 = cb[n15], cb1 = cb[16 + n15], cb2 = cb[32 + n15], cb3 = cb[48 + n15];

    int sprev = -1;
    float am0 = 0.f, am1 = 0.f, am2 = 0.f, am3 = 0.f;

    int eg = base;
    int s = esrc[eg], d = edst[eg];
    uint4 A0, A1, A2, A3, A4;
    load_A(h16, ef16, s, d, eg, quad, A0, A1, A2, A3, A4);
    int egn = base + 4;
    int sn = esrc[egn], dn = edst[egn];

    for (int g = 0; g < NGROUPS; g++) {
        int s_cur = s;

        floatx4 acc[8];
#pragma unroll
        for (int t = 0; t < 8; t++) acc[t] = (floatx4){0.f, 0.f, 0.f, 0.f};

        half8 a0 = __builtin_bit_cast(half8, A0);
        half8 a1 = __builtin_bit_cast(half8, A1);
        half8 a2 = __builtin_bit_cast(half8, A2);
        half8 a3 = __builtin_bit_cast(half8, A3);
        half8 a4 = __builtin_bit_cast(half8, A4);
#pragma unroll
        for (int t = 0; t < 8; t++) acc[t] = __builtin_amdgcn_mfma_f32_16x16x32_f16(a0, B[t][0], acc[t], 0, 0, 0);
#pragma unroll
        for (int t = 0; t < 8; t++) acc[t] = __builtin_amdgcn_mfma_f32_16x16x32_f16(a1, B[t][1], acc[t], 0, 0, 0);
#pragma unroll
        for (int t = 0; t < 8; t++) acc[t] = __builtin_amdgcn_mfma_f32_16x16x32_f16(a2, B[t][2], acc[t], 0, 0, 0);
#pragma unroll
        for (int t = 0; t < 8; t++) acc[t] = __builtin_amdgcn_mfma_f32_16x16x32_f16(a3, B[t][3], acc[t], 0, 0, 0);
#pragma unroll
        for (int t = 0; t < 8; t++) acc[t] = __builtin_amdgcn_mfma_f32_16x16x32_f16(a4, B[t][4], acc[t], 0, 0, 0);

        int egc = base + ((g + 1 < NGROUPS) ? (g + 1) * 4 : g * 4);
        load_A(h16, ef16, sn, dn, egc, quad, A0, A1, A2, A3, A4);
        s = sn; d = dn;
        int eg2 = base + ((g + 2 < NGROUPS) ? (g + 2) * 4 : (NGROUPS - 1) * 4);
        sn = esrc[eg2]; dn = edst[eg2];

#pragma unroll
        for (int r = 0; r < 4; r++) {
            int sr = __shfl(s_cur, quad * 4 + r, 64);
            if (sr != sprev) {
                if (sprev >= 0) {
                    float* p = agg + (size_t)sprev * HH + n15;
                    atomicAdd(p, am0);
                    atomicAdd(p + 16, am1);
                    atomicAdd(p + 32, am2);
                    atomicAdd(p + 48, am3);
                }
                sprev = sr;
                am0 = am1 = am2 = am3 = 0.f;
            }
            am0 += sigmoid_fast(acc[0][r] + gb0) * softplus_fast(acc[4][r] + cb0);
            am1 += sigmoid_fast(acc[1][r] + gb1) * softplus_fast(acc[5][r] + cb1);
            am2 += sigmoid_fast(acc[2][r] + gb2) * softplus_fast(acc[6][r] + cb2);
            am3 += sigmoid_fast(acc[3][r] + gb3) * softplus_fast(acc[7][r] + cb3);
        }
    }
    if (sprev >= 0) {
        float* p = agg + (size_t)sprev * HH + n15;
        atomicAdd(p, am0);
        atomicAdd(p + 16, am1);
        atomicAdd(p + 32, am2);
        atomicAdd(p + 48, am3);
    }
}

// ---------------- BN ----------------
__global__ __launch_bounds__(256)
void bn_stats_kernel(const float* __restrict__ agg, float* __restrict__ stats, int total) {
    __shared__ float ls[256], lss[256];
    int tid = threadIdx.x;
    float s = 0.f, ss = 0.f;
    for (int idx = blockIdx.x * 256 + tid; idx < total; idx += gridDim.x * 256) {
        float v = agg[idx];
        s += v;
        ss += v * v;
    }
    ls[tid] = s;
    lss[tid] = ss;
    __syncthreads();
    if (tid < 64) {
        s = ls[tid] + ls[tid + 64] + ls[tid + 128] + ls[tid + 192];
        ss = lss[tid] + lss[tid + 64] + lss[tid + 128] + lss[tid + 192];
        atomicAdd(&stats[tid], s);
        atomicAdd(&stats[64 + tid], ss);
    }
}

// h = softplus(h + BN(agg)); also zeroes agg for the next conv layer
__global__ __launch_bounds__(256)
void bn_update_kernel(float* __restrict__ h, _Float16* __restrict__ h16,
                      float* __restrict__ agg,
                      const float* __restrict__ stats,
                      const float* __restrict__ g, const float* __restrict__ b,
                      int total, float invN) {
    int idx = blockIdx.x * 256 + threadIdx.x;
    if (idx >= total) return;
    int j = idx & 63;
    float mu = stats[j] * invN;
    float var = stats[64 + j] * invN - mu * mu;
    var = fmaxf(var, 0.0f);
    float scale = g[j] * rsqrtf(var + EPSBN);
    float a = agg[idx];
    agg[idx] = 0.f;  // pre-zero for next conv (replaces memset dispatch)
    float v = h[idx] + (a - mu) * scale + b[j];
    float hv = softplus_fast(v);
    h[idx] = hv;
    h16[idx] = (_Float16)hv;
}

// ---------------- pool ----------------
__global__ __launch_bounds__(256)
void pool_kernel(const float* __restrict__ h, const int* __restrict__ gi,
                 float* __restrict__ pool, float* __restrict__ counts, int n) {
    int tid = threadIdx.x;
    int grp = tid >> 6;
    int j = tid & 63;
    int n0 = blockIdx.x * 64 + grp * 16;
    if (n0 >= n) return;
    int nend = n0 + 16; if (nend > n) nend = n;
    int gprev = gi[n0];
    float a = 0.f;
    int cnt = 0;
    for (int nn = n0; nn < nend; nn++) {
        int gg = gi[nn];
        if (gg != gprev) {
            atomicAdd(&pool[gprev * 64 + j], a);
            if (j == 0) atomicAdd(&counts[gprev], (float)cnt);
            a = 0.f; cnt = 0; gprev = gg;
        }
        a += h[(size_t)nn * 64 + j];
        cnt++;
    }
    atomicAdd(&pool[gprev * 64 + j], a);
    if (j == 0) atomicAdd(&counts[gprev], (float)cnt);
}

__global__ __launch_bounds__(128)
void mlp_kernel(const float* __restrict__ pool, const float* __restrict__ counts,
                const float* __restrict__ w1, const float* __restrict__ b1,
                const float* __restrict__ w2, const float* __restrict__ b2,
                const float* __restrict__ w3, const float* __restrict__ b3,
                float* __restrict__ out) {
    __shared__ float x0[64], x1[128], x2[64];
    int b = blockIdx.x, t = threadIdx.x;
    if (t < 64) {
        float c = counts[b];
        c = c < 1.f ? 1.f : c;
        x0[t] = pool[b * 64 + t] / c;
    }
    __syncthreads();
    {
        float acc = 0.f;
#pragma unroll
        for (int k = 0; k < 64; k++) acc += x0[k] * w1[k * 128 + t];
        x1[t] = softplus_fast(acc + b1[t]);
    }
    __syncthreads();
    if (t < 64) {
        float acc = 0.f;
#pragma unroll
        for (int k = 0; k < 128; k++) acc += x1[k] * w2[k * 64 + t];
        x2[t] = softplus_fast(acc + b2[t]);
    }
    __syncthreads();
    if (t == 0) {
        float acc = 0.f;
        for (int k = 0; k < 64; k++) acc += x2[k] * w3[k];
        out[b] = acc + b3[0];
    }
}

extern "C" void kernel_launch(void* const* d_in, const int* in_sizes, int n_in,
                              void* d_out, int out_size, void* d_ws, size_t ws_size,
                              hipStream_t stream) {
    const float* nf      = (const float*)d_in[0];
    const int*   ei      = (const int*)d_in[1];
    const float* ef      = (const float*)d_in[2];
    const int*   gi      = (const int*)d_in[3];
    const float* embed_w = (const float*)d_in[4];
    const float* embed_b = (const float*)d_in[5];
    const float* gate_w  = (const float*)d_in[6];
    const float* gate_b  = (const float*)d_in[7];
    const float* cand_w  = (const float*)d_in[8];
    const float* cand_b  = (const float*)d_in[9];
    const float* bn_g    = (const float*)d_in[10];
    const float* bn_b    = (const float*)d_in[11];
    const float* w1      = (const float*)d_in[12];
    const float* b1      = (const float*)d_in[13];
    const float* w2      = (const float*)d_in[14];
    const float* b2      = (const float*)d_in[15];
    const float* w3      = (const float*)d_in[16];
    const float* b3      = (const float*)d_in[17];
    float* out = (float*)d_out;

    const int NH = NN * HH;  // 6.4M
    char* p = (char*)d_ws;
    // --- zero-initialized block (single memset) ---
    int*       offs    = (int*)p;              p += (size_t)NN * 4;
    float*     agg     = (float*)p;            p += (size_t)NH * 4;
    float*     stats   = (float*)p;            p += 3 * 128 * 4;
    float*     pool    = (float*)p;            p += (size_t)BB * HH * 4;
    float*     counts  = (float*)p;            p += (size_t)BB * 4;
    size_t zero_bytes = (size_t)(p - (char*)d_ws);
    // --- rest ---
    float*     h       = (float*)p;            p += (size_t)NH * 4;
    _Float16*  h16     = (_Float16*)p;         p += (size_t)NH * 2;
    int*       ssorted = (int*)p;              p += (size_t)EE * 4;
    int*       dsorted = (int*)p;              p += (size_t)EE * 4;
    _Float16*  ef16    = (_Float16*)p;         p += (size_t)EE * EFSTR * 2;
    int*       perm    = (int*)p;              p += (size_t)EE * 4;
    int*       rank    = (int*)p;              p += (size_t)EE * 4;
    _Float16*  wTall   = (_Float16*)p;         p += (size_t)3 * 128 * 160 * 2;
    int*       bsum    = (int*)p;              p += 512 * 4;

    const int* src = ei;
    const int* dst = ei + EE;

    hipMemsetAsync(d_ws, 0, zero_bytes, stream);

    // ---- sort edges by src + weight prep ----
    hist_rank_kernel<<<EE / 256, 256, 0, stream>>>(src, offs, rank);
    prep_w_kernel<<<(3 * 128 * 160 + 255) / 256, 256, 0, stream>>>(gate_w, cand_w, wTall);
    scan1_kernel<<<NB1, 256, 0, stream>>>(offs, bsum, NN);
    scan2_kernel<<<1, 512, 0, stream>>>(bsum, NB1);
    scan3_kernel<<<NB1, 256, 0, stream>>>(offs, bsum, NN);
    perm_kernel<<<EE / 256, 256, 0, stream>>>(src, rank, offs, perm);
    gather_kernel<<<EE / 256, 256, 0, stream>>>(perm, src, dst, ef, ssorted, dsorted, ef16);

    // ---- embed ----
    embed_kernel<<<NH / 256, 256, 0, stream>>>(nf, embed_w, embed_b, h, h16, NN);

    // ---- conv layers (agg zeroed by memset for i=0, by bn_update after) ----
    for (int i = 0; i < N_CONV; i++) {
        edge_conv_mfma<<<NWAVES, 64, 0, stream>>>(
            h16, ssorted, dsorted, ef16,
            wTall + (size_t)i * 128 * 160,
            gate_b + i * HH, cand_b + i * HH, agg);
        bn_stats_kernel<<<512, 256, 0, stream>>>(agg, stats + i * 128, NH);
        bn_update_kernel<<<NH / 256, 256, 0, stream>>>(
            h, h16, agg, stats + i * 128, bn_g + i * HH, bn_b + i * HH, NH, 1.0f / (float)NN);
    }

    // ---- pool + MLP ----
    pool_kernel<<<(NN + 63) / 64, 256, 0, stream>>>(h, gi, pool, counts, NN);
    mlp_kernel<<<BB, 128, 0, stream>>>(pool, counts, w1, b1, w2, b2, w3, b3, out);
}

// Round 6
// 882.989 us; speedup vs baseline: 7.7724x; 1.0136x over previous
//
#include <hip/hip_runtime.h>
#include <hip/hip_bf16.h>

#define NN 100000
#define EE 1600000
#define BB 256
#define F_NODE 35
#define F_EDGE 10
#define HH 64
#define IN_DIM 138
#define N_CONV 3
#define EPSBN 1e-5f
#define NB1 ((NN + 255) / 256)  // 391 scan blocks

// conv tiling: 4000 blocks x 2 waves; block covers 400 edges (waves split cols)
#define NBLK 4000
#define NGROUPS 25
#define SUBLEN 100          // 4*NGROUPS
#define EPB 400             // 16*NGROUPS edges per block
#define EFSTR 12            // padded ef row in halves (24 B)

typedef _Float16 half8 __attribute__((ext_vector_type(8)));
typedef float floatx4 __attribute__((ext_vector_type(4)));

__device__ __forceinline__ float softplus_fast(float x) {
    return fmaxf(x, 0.0f) + __logf(1.0f + __expf(-fabsf(x)));
}
__device__ __forceinline__ float sigmoid_fast(float x) {
    return __builtin_amdgcn_rcpf(1.0f + __expf(-x));
}

// ---------------- sort by src: hist+rank, scan, perm(+scan3), gather ----------------
__global__ __launch_bounds__(256)
void hist_rank_kernel(const int* __restrict__ src, int* __restrict__ cnt,
                      int* __restrict__ rank) {
    int e = blockIdx.x * 256 + threadIdx.x;
    rank[e] = atomicAdd(&cnt[src[e]], 1);
}

__global__ __launch_bounds__(256)
void scan1_kernel(int* __restrict__ cnt, int* __restrict__ bsum, int n) {
    __shared__ int ls[256];
    int t = threadIdx.x;
    int i = blockIdx.x * 256 + t;
    int v = (i < n) ? cnt[i] : 0;
    ls[t] = v;
    __syncthreads();
#pragma unroll
    for (int off = 1; off < 256; off <<= 1) {
        int add = (t >= off) ? ls[t - off] : 0;
        __syncthreads();
        ls[t] += add;
        __syncthreads();
    }
    if (i < n) cnt[i] = ls[t] - v;
    if (t == 255) bsum[blockIdx.x] = ls[255];
}

__global__ __launch_bounds__(512)
void scan2_kernel(int* __restrict__ bsum, int nb) {
    __shared__ int ls[512];
    int t = threadIdx.x;
    int v = (t < nb) ? bsum[t] : 0;
    ls[t] = v;
    __syncthreads();
#pragma unroll
    for (int off = 1; off < 512; off <<= 1) {
        int add = (t >= off) ? ls[t - off] : 0;
        __syncthreads();
        ls[t] += add;
        __syncthreads();
    }
    if (t < nb) bsum[t] = ls[t] - v;
}

// perm[offs[s] + bsum[s>>8] + rank[e]] = e  (scan3 folded in)
__global__ __launch_bounds__(256)
void perm_kernel(const int* __restrict__ src, const int* __restrict__ rank,
                 const int* __restrict__ offs, const int* __restrict__ bsum,
                 int* __restrict__ perm) {
    int e = blockIdx.x * 256 + threadIdx.x;
    int s = src[e];
    perm[offs[s] + bsum[s >> 8] + rank[e]] = e;
}

// coalesced-write gather into sorted arrays; ef -> f16 padded to 12 halves
__global__ __launch_bounds__(256)
void gather_kernel(const int* __restrict__ perm,
                   const int* __restrict__ src, const int* __restrict__ dst,
                   const float* __restrict__ ef,
                   int* __restrict__ ssorted, int* __restrict__ dsorted,
                   _Float16* __restrict__ ef16) {
    int pos = blockIdx.x * 256 + threadIdx.x;
    int e = perm[pos];
    ssorted[pos] = src[e];
    dsorted[pos] = dst[e];
    const float2* efe = (const float2*)(ef + (size_t)e * F_EDGE);
    uint* op = (uint*)(ef16 + (size_t)pos * EFSTR);
#pragma unroll
    for (int i = 0; i < 5; i++) {
        float2 v = efe[i];
        _Float16 h0 = (_Float16)v.x;
        _Float16 h1 = (_Float16)v.y;
        op[i] = (uint)*(unsigned short*)&h0 | ((uint)*(unsigned short*)&h1 << 16);
    }
    op[5] = 0u;
}

// weights -> f16 transposed [layer][n=0..127][k=0..159], zero-padded K
__global__ __launch_bounds__(256)
void prep_w_kernel(const float* __restrict__ gw, const float* __restrict__ cw,
                   _Float16* __restrict__ wT) {
    int idx = blockIdx.x * 256 + threadIdx.x;
    if (idx >= 3 * 128 * 160) return;
    int k = idx % 160;
    int n = (idx / 160) & 127;
    int layer = idx / (160 * 128);
    float v = 0.f;
    if (k < IN_DIM)
        v = (n < 64) ? gw[layer * IN_DIM * HH + k * HH + n]
                     : cw[layer * IN_DIM * HH + k * HH + (n - 64)];
    wT[idx] = (_Float16)v;
}

// ---------------- embed ----------------
__global__ __launch_bounds__(256)
void embed_kernel(const float* __restrict__ nf, const float* __restrict__ w,
                  const float* __restrict__ bias, float* __restrict__ h,
                  _Float16* __restrict__ h16, int n) {
    __shared__ float wl[F_NODE * HH];
    int tid = threadIdx.x;
    for (int i = tid; i < F_NODE * HH; i += 256) wl[i] = w[i];
    __syncthreads();
    int idx = blockIdx.x * 256 + tid;
    int node = idx >> 6, j = idx & 63;
    if (node >= n) return;
    float acc = bias[j];
    const float* row = nf + node * F_NODE;
#pragma unroll
    for (int k = 0; k < F_NODE; k++) acc += row[k] * wl[k * HH + j];
    h[idx] = acc;
    h16[idx] = (_Float16)acc;
}

// ---------------- conv: barrier-free, LDS-free, col-split across 2 waves ----------------
__device__ __forceinline__ void load_A(const _Float16* __restrict__ h16,
                                       const _Float16* __restrict__ ef16,
                                       int s, int d, int eg, int quad,
                                       uint4& A0, uint4& A1, uint4& A2, uint4& A3,
                                       uint4& A4) {
    const uint4* hs = (const uint4*)(h16 + (size_t)s * HH);
    const uint4* hd = (const uint4*)(h16 + (size_t)d * HH);
    A0 = hs[quad];
    A1 = hs[quad + 4];
    A2 = hd[quad];
    A3 = hd[quad + 4];
    uint4 z; z.x = z.y = z.z = z.w = 0u;
    A4 = z;
    const _Float16* p = ef16 + (size_t)eg * EFSTR;
    if (quad == 0) {
        uint2 a = *(const uint2*)p;
        uint2 b = *(const uint2*)(p + 4);
        A4.x = a.x; A4.y = a.y; A4.z = b.x; A4.w = b.y;
    } else if (quad == 1) {
        uint2 a = *(const uint2*)(p + 8);
        A4.x = a.x; A4.y = a.y;
    }
}

__global__ __launch_bounds__(128, 3)
void edge_conv_mfma(const _Float16* __restrict__ h16,
                    const int* __restrict__ esrc,
                    const int* __restrict__ edst,
                    const _Float16* __restrict__ ef16,
                    const _Float16* __restrict__ wT,
                    const float* __restrict__ gb, const float* __restrict__ cb,
                    float* __restrict__ agg) {
    int lane = threadIdx.x & 63;
    int w = threadIdx.x >> 6;          // wave 0/1: col-split
    int quad = lane >> 4, n15 = lane & 15;
    int base = blockIdx.x * EPB + ((n15 >> 2) * SUBLEN) + (n15 & 3);

    // this wave's 4 B-tiles: gate {2w,2w+1}, cand {4+2w,4+2w+1} -> 80 VGPRs
    int tg = 2 * w;
    half8 B[4][5];
#pragma unroll
    for (int j = 0; j < 2; j++) {
        const _Float16* wrg = wT + ((tg + j) * 16 + n15) * 160 + quad * 8;
        const _Float16* wrc = wT + ((4 + tg + j) * 16 + n15) * 160 + quad * 8;
#pragma unroll
        for (int ks = 0; ks < 5; ks++) {
            B[j][ks]     = *(const half8*)(wrg + ks * 32);
            B[2 + j][ks] = *(const half8*)(wrc + ks * 32);
        }
    }
    float gb0 = gb[tg * 16 + n15], gb1 = gb[(tg + 1) * 16 + n15];
    float cb0 = cb[tg * 16 + n15], cb1 = cb[(tg + 1) * 16 + n15];
    int colbase = tg * 16 + n15;

    int sprev = -1;
    float am0 = 0.f, am1 = 0.f;

    int eg = base;
    int s = esrc[eg], d = edst[eg];
    uint4 A0, A1, A2, A3, A4;
    load_A(h16, ef16, s, d, eg, quad, A0, A1, A2, A3, A4);
    int egn = base + 4;
    int sn = esrc[egn], dn = edst[egn];

    for (int g = 0; g < NGROUPS; g++) {
        int s_cur = s;

        floatx4 acc[4];
#pragma unroll
        for (int t = 0; t < 4; t++) acc[t] = (floatx4){0.f, 0.f, 0.f, 0.f};

        half8 a0 = __builtin_bit_cast(half8, A0);
        half8 a1 = __builtin_bit_cast(half8, A1);
        half8 a2 = __builtin_bit_cast(half8, A2);
        half8 a3 = __builtin_bit_cast(half8, A3);
        half8 a4 = __builtin_bit_cast(half8, A4);
#pragma unroll
        for (int t = 0; t < 4; t++) acc[t] = __builtin_amdgcn_mfma_f32_16x16x32_f16(a0, B[t][0], acc[t], 0, 0, 0);
#pragma unroll
        for (int t = 0; t < 4; t++) acc[t] = __builtin_amdgcn_mfma_f32_16x16x32_f16(a1, B[t][1], acc[t], 0, 0, 0);
#pragma unroll
        for (int t = 0; t < 4; t++) acc[t] = __builtin_amdgcn_mfma_f32_16x16x32_f16(a2, B[t][2], acc[t], 0, 0, 0);
#pragma unroll
        for (int t = 0; t < 4; t++) acc[t] = __builtin_amdgcn_mfma_f32_16x16x32_f16(a3, B[t][3], acc[t], 0, 0, 0);
#pragma unroll
        for (int t = 0; t < 4; t++) acc[t] = __builtin_amdgcn_mfma_f32_16x16x32_f16(a4, B[t][4], acc[t], 0, 0, 0);

        int egc = base + ((g + 1 < NGROUPS) ? (g + 1) * 4 : g * 4);
        load_A(h16, ef16, sn, dn, egc, quad, A0, A1, A2, A3, A4);
        s = sn; d = dn;
        int eg2 = base + ((g + 2 < NGROUPS) ? (g + 2) * 4 : (NGROUPS - 1) * 4);
        sn = esrc[eg2]; dn = edst[eg2];

#pragma unroll
        for (int r = 0; r < 4; r++) {
            int sr = __shfl(s_cur, quad * 4 + r, 64);
            if (sr != sprev) {
                if (sprev >= 0) {
                    float* p = agg + (size_t)sprev * HH + colbase;
                    atomicAdd(p, am0);
                    atomicAdd(p + 16, am1);
                }
                sprev = sr;
                am0 = am1 = 0.f;
            }
            am0 += sigmoid_fast(acc[0][r] + gb0) * softplus_fast(acc[2][r] + cb0);
            am1 += sigmoid_fast(acc[1][r] + gb1) * softplus_fast(acc[3][r] + cb1);
        }
    }
    if (sprev >= 0) {
        float* p = agg + (size_t)sprev * HH + colbase;
        atomicAdd(p, am0);
        atomicAdd(p + 16, am1);
    }
}

// ---------------- BN ----------------
__global__ __launch_bounds__(256)
void bn_stats_kernel(const float* __restrict__ agg, float* __restrict__ stats, int total) {
    __shared__ float ls[256], lss[256];
    int tid = threadIdx.x;
    float s = 0.f, ss = 0.f;
    for (int idx = blockIdx.x * 256 + tid; idx < total; idx += gridDim.x * 256) {
        float v = agg[idx];
        s += v;
        ss += v * v;
    }
    ls[tid] = s;
    lss[tid] = ss;
    __syncthreads();
    if (tid < 64) {
        s = ls[tid] + ls[tid + 64] + ls[tid + 128] + ls[tid + 192];
        ss = lss[tid] + lss[tid + 64] + lss[tid + 128] + lss[tid + 192];
        atomicAdd(&stats[tid], s);
        atomicAdd(&stats[64 + tid], ss);
    }
}

// h = softplus(h + BN(agg)); also zeroes agg for the next conv layer
__global__ __launch_bounds__(256)
void bn_update_kernel(float* __restrict__ h, _Float16* __restrict__ h16,
                      float* __restrict__ agg,
                      const float* __restrict__ stats,
                      const float* __restrict__ g, const float* __restrict__ b,
                      int total, float invN) {
    int idx = blockIdx.x * 256 + threadIdx.x;
    if (idx >= total) return;
    int j = idx & 63;
    float mu = stats[j] * invN;
    float var = stats[64 + j] * invN - mu * mu;
    var = fmaxf(var, 0.0f);
    float scale = g[j] * rsqrtf(var + EPSBN);
    float a = agg[idx];
    agg[idx] = 0.f;
    float v = h[idx] + (a - mu) * scale + b[j];
    float hv = softplus_fast(v);
    h[idx] = hv;
    h16[idx] = (_Float16)hv;
}

// ---------------- pool ----------------
__global__ __launch_bounds__(256)
void pool_kernel(const float* __restrict__ h, const int* __restrict__ gi,
                 float* __restrict__ pool, float* __restrict__ counts, int n) {
    int tid = threadIdx.x;
    int grp = tid >> 6;
    int j = tid & 63;
    int n0 = blockIdx.x * 64 + grp * 16;
    if (n0 >= n) return;
    int nend = n0 + 16; if (nend > n) nend = n;
    int gprev = gi[n0];
    float a = 0.f;
    int cnt = 0;
    for (int nn = n0; nn < nend; nn++) {
        int gg = gi[nn];
        if (gg != gprev) {
            atomicAdd(&pool[gprev * 64 + j], a);
            if (j == 0) atomicAdd(&counts[gprev], (float)cnt);
            a = 0.f; cnt = 0; gprev = gg;
        }
        a += h[(size_t)nn * 64 + j];
        cnt++;
    }
    atomicAdd(&pool[gprev * 64 + j], a);
    if (j == 0) atomicAdd(&counts[gprev], (float)cnt);
}

__global__ __launch_bounds__(128)
void mlp_kernel(const float* __restrict__ pool, const float* __restrict__ counts,
                const float* __restrict__ w1, const float* __restrict__ b1,
                const float* __restrict__ w2, const float* __restrict__ b2,
                const float* __restrict__ w3, const float* __restrict__ b3,
                float* __restrict__ out) {
    __shared__ float x0[64], x1[128], x2[64];
    int b = blockIdx.x, t = threadIdx.x;
    if (t < 64) {
        float c = counts[b];
        c = c < 1.f ? 1.f : c;
        x0[t] = pool[b * 64 + t] / c;
    }
    __syncthreads();
    {
        float acc = 0.f;
#pragma unroll
        for (int k = 0; k < 64; k++) acc += x0[k] * w1[k * 128 + t];
        x1[t] = softplus_fast(acc + b1[t]);
    }
    __syncthreads();
    if (t < 64) {
        float acc = 0.f;
#pragma unroll
        for (int k = 0; k < 128; k++) acc += x1[k] * w2[k * 64 + t];
        x2[t] = softplus_fast(acc + b2[t]);
    }
    __syncthreads();
    if (t == 0) {
        float acc = 0.f;
        for (int k = 0; k < 64; k++) acc += x2[k] * w3[k];
        out[b] = acc + b3[0];
    }
}

extern "C" void kernel_launch(void* const* d_in, const int* in_sizes, int n_in,
                              void* d_out, int out_size, void* d_ws, size_t ws_size,
                              hipStream_t stream) {
    const float* nf      = (const float*)d_in[0];
    const int*   ei      = (const int*)d_in[1];
    const float* ef      = (const float*)d_in[2];
    const int*   gi      = (const int*)d_in[3];
    const float* embed_w = (const float*)d_in[4];
    const float* embed_b = (const float*)d_in[5];
    const float* gate_w  = (const float*)d_in[6];
    const float* gate_b  = (const float*)d_in[7];
    const float* cand_w  = (const float*)d_in[8];
    const float* cand_b  = (const float*)d_in[9];
    const float* bn_g    = (const float*)d_in[10];
    const float* bn_b    = (const float*)d_in[11];
    const float* w1      = (const float*)d_in[12];
    const float* b1      = (const float*)d_in[13];
    const float* w2      = (const float*)d_in[14];
    const float* b2      = (const float*)d_in[15];
    const float* w3      = (const float*)d_in[16];
    const float* b3      = (const float*)d_in[17];
    float* out = (float*)d_out;

    const int NH = NN * HH;  // 6.4M
    char* p = (char*)d_ws;
    // --- zero-initialized block (single memset) ---
    int*       offs    = (int*)p;              p += (size_t)NN * 4;
    float*     agg     = (float*)p;            p += (size_t)NH * 4;
    float*     stats   = (float*)p;            p += 3 * 128 * 4;
    float*     pool    = (float*)p;            p += (size_t)BB * HH * 4;
    float*     counts  = (float*)p;            p += (size_t)BB * 4;
    size_t zero_bytes = (size_t)(p - (char*)d_ws);
    // --- rest ---
    float*     h       = (float*)p;            p += (size_t)NH * 4;
    _Float16*  h16     = (_Float16*)p;         p += (size_t)NH * 2;
    int*       ssorted = (int*)p;              p += (size_t)EE * 4;
    int*       dsorted = (int*)p;              p += (size_t)EE * 4;
    _Float16*  ef16    = (_Float16*)p;         p += (size_t)EE * EFSTR * 2;
    int*       perm    = (int*)p;              p += (size_t)EE * 4;
    int*       rank    = (int*)p;              p += (size_t)EE * 4;
    _Float16*  wTall   = (_Float16*)p;         p += (size_t)3 * 128 * 160 * 2;
    int*       bsum    = (int*)p;              p += 512 * 4;

    const int* src = ei;
    const int* dst = ei + EE;

    hipMemsetAsync(d_ws, 0, zero_bytes, stream);

    // ---- sort edges by src + weight prep ----
    hist_rank_kernel<<<EE / 256, 256, 0, stream>>>(src, offs, rank);
    prep_w_kernel<<<(3 * 128 * 160 + 255) / 256, 256, 0, stream>>>(gate_w, cand_w, wTall);
    scan1_kernel<<<NB1, 256, 0, stream>>>(offs, bsum, NN);
    scan2_kernel<<<1, 512, 0, stream>>>(bsum, NB1);
    perm_kernel<<<EE / 256, 256, 0, stream>>>(src, rank, offs, bsum, perm);
    gather_kernel<<<EE / 256, 256, 0, stream>>>(perm, src, dst, ef, ssorted, dsorted, ef16);

    // ---- embed ----
    embed_kernel<<<NH / 256, 256, 0, stream>>>(nf, embed_w, embed_b, h, h16, NN);

    // ---- conv layers ----
    for (int i = 0; i < N_CONV; i++) {
        edge_conv_mfma<<<NBLK, 128, 0, stream>>>(
            h16, ssorted, dsorted, ef16,
            wTall + (size_t)i * 128 * 160,
            gate_b + i * HH, cand_b + i * HH, agg);
        bn_stats_kernel<<<512, 256, 0, stream>>>(agg, stats + i * 128, NH);
        bn_update_kernel<<<NH / 256, 256, 0, stream>>>(
            h, h16, agg, stats + i * 128, bn_g + i * HH, bn_b + i * HH, NH, 1.0f / (float)NN);
    }

    // ---- pool + MLP ----
    pool_kernel<<<(NN + 63) / 64, 256, 0, stream>>>(h, gi, pool, counts, NN);
    mlp_kernel<<<BB, 128, 0, stream>>>(pool, counts, w1, b1, w2, b2, w3, b3, out);
}